// Round 10
// baseline (302.544 us; speedup 1.0000x reference)
//
#include <hip/hip_runtime.h>
#include <hip/hip_bf16.h>
#include <math.h>

#define B1 2048
#define B2 8192
#define NH 12
#define DH 64
#define DMODEL 768

typedef __attribute__((ext_vector_type(8))) short short8;
typedef __attribute__((ext_vector_type(4))) float floatx4;
typedef __attribute__((ext_vector_type(8))) unsigned short ushort8;
typedef __attribute__((ext_vector_type(4))) unsigned short ushort4v;

static __device__ __forceinline__ unsigned short f2bf(float f) {
  __bf16 b = (__bf16)f;
  return __builtin_bit_cast(unsigned short, b);
}
static __device__ __forceinline__ float bf2f(unsigned short u) {
  return __builtin_bit_cast(float, ((unsigned)u) << 16);
}

// async global->LDS, 16B per lane; LDS dest = wave-uniform base + lane*16
static __device__ __forceinline__ void gload16(const unsigned short* g,
                                               unsigned short* l) {
  __builtin_amdgcn_global_load_lds(
      (const __attribute__((address_space(1))) void*)g,
      (__attribute__((address_space(3))) void*)l, 16, 0, 0);
}

// ---------------------------------------------------------------------------
// Fused prep: fp32 -> bf16. x1/x2: hi only (x-residual dropped; see qkv_proj
// precision note). Wq/Wk: hi+lo split. Wv/Wo: hi only.
// block-role table: [0,1536) x1 | [1536,7680) x2 | [7680,8256) Wq |
// [8256,8832) Wk | [8832,9408) Wv | [9408,9984) Wo
// ---------------------------------------------------------------------------
__global__ __launch_bounds__(256) void prep_all(
    const float* __restrict__ x1, unsigned short* __restrict__ x1h,
    const float* __restrict__ x2, unsigned short* __restrict__ x2h,
    const float* __restrict__ Wq, unsigned short* __restrict__ Wqh,
    unsigned short* __restrict__ Wql, const float* __restrict__ Wk,
    unsigned short* __restrict__ Wkh, unsigned short* __restrict__ Wkl,
    const float* __restrict__ Wv, unsigned short* __restrict__ Wvh,
    const float* __restrict__ Wo, unsigned short* __restrict__ Woh) {
  const int bi = blockIdx.x;
  const float* src;
  unsigned short *hi, *lo = nullptr;
  int lb;
  if (bi < 1536) {
    src = x1; hi = x1h; lb = bi;
  } else if (bi < 7680) {
    src = x2; hi = x2h; lb = bi - 1536;
  } else if (bi < 8256) {
    src = Wq; hi = Wqh; lo = Wql; lb = bi - 7680;
  } else if (bi < 8832) {
    src = Wk; hi = Wkh; lo = Wkl; lb = bi - 8256;
  } else if (bi < 9408) {
    src = Wv; hi = Wvh; lb = bi - 8832;
  } else {
    src = Wo; hi = Woh; lb = bi - 9408;
  }
  const int i = (lb * 256 + threadIdx.x) * 4;
  const float4 v = *(const float4*)&src[i];
  ushort4v h = {f2bf(v.x), f2bf(v.y), f2bf(v.z), f2bf(v.w)};
  *(ushort4v*)&hi[i] = h;
  if (lo) {
    ushort4v l = {f2bf(v.x - bf2f(h[0])), f2bf(v.y - bf2f(h[1])),
                  f2bf(v.z - bf2f(h[2])), f2bf(v.w - bf2f(h[3]))};
    *(ushort4v*)&lo[i] = l;
  }
}

// ---------------------------------------------------------------------------
// Core bf16 MFMA GEMM tile: C[M,N] = A[M,K]*B[N,K]^T (both K-contiguous).
// 128x128 tile, BK=32, 4 waves (2x2), 64x64/wave, global_load_lds staging,
// XOR-swizzled granules.
// BSPLIT: B held as hi+lo, 2-MFMA k-step => C = A_bf16 * B_full.
//   (A-residual term dropped: A is bf16-rounded downstream anyway, so the
//    extra 2^-9 relative error only raises operand error by ~sqrt(2).)
// L2N: per-64-col L2 norm epilogue.
// ---------------------------------------------------------------------------
template <bool BSPLIT, bool L2N, bool F32OUT>
static __device__ __forceinline__ void gemm_tile(
    const unsigned short* __restrict__ Ahg,
    const unsigned short* __restrict__ Bhg,
    const unsigned short* __restrict__ Blg,
    void* __restrict__ Cv, int M, int N, int K, int m0, int n0,
    unsigned short* sAh, unsigned short* sBh, unsigned short* sBl) {
  const int tid = threadIdx.x;
  const int wave = tid >> 6;
  const int lane = tid & 63;
  const int wm = wave >> 1;
  const int wn = wave & 1;
  const int n15 = lane & 15;
  const int quad = lane >> 4;
  const int srow = lane >> 2;
  const int cpl = (lane & 3) ^ (srow >> 2);

  floatx4 acc[4][4];
#pragma unroll
  for (int i = 0; i < 4; ++i)
#pragma unroll
    for (int j = 0; j < 4; ++j) acc[i][j] = (floatx4){0.f, 0.f, 0.f, 0.f};

  for (int k0 = 0; k0 < K; k0 += 32) {
    __syncthreads();
#pragma unroll
    for (int jj = 0; jj < 2; ++jj) {
      const int j = wave * 2 + jj;
      const int row = j * 16 + srow;
      const size_t goffA = (size_t)(m0 + row) * K + k0 + cpl * 8;
      const size_t goffB = (size_t)(n0 + row) * K + k0 + cpl * 8;
      gload16(Ahg + goffA, &sAh[j * 512]);
      gload16(Bhg + goffB, &sBh[j * 512]);
      if constexpr (BSPLIT) {
        gload16(Blg + goffB, &sBl[j * 512]);
      }
    }
    __syncthreads();

    short8 afh[4];
#pragma unroll
    for (int mt = 0; mt < 4; ++mt) {
      const int row = wm * 64 + mt * 16 + n15;
      const int off = row * 32 + ((quad ^ (n15 >> 2)) << 3);
      afh[mt] = *(const short8*)&sAh[off];
    }
#pragma unroll
    for (int nt = 0; nt < 4; ++nt) {
      const int row = wn * 64 + nt * 16 + n15;
      const int off = row * 32 + ((quad ^ (n15 >> 2)) << 3);
      const short8 bfh = *(const short8*)&sBh[off];
      if constexpr (BSPLIT) {
        const short8 bfl = *(const short8*)&sBl[off];
#pragma unroll
        for (int mt = 0; mt < 4; ++mt) {
          acc[mt][nt] = __builtin_amdgcn_mfma_f32_16x16x32_bf16(afh[mt], bfh, acc[mt][nt], 0, 0, 0);
          acc[mt][nt] = __builtin_amdgcn_mfma_f32_16x16x32_bf16(afh[mt], bfl, acc[mt][nt], 0, 0, 0);
        }
      } else {
#pragma unroll
        for (int mt = 0; mt < 4; ++mt)
          acc[mt][nt] = __builtin_amdgcn_mfma_f32_16x16x32_bf16(afh[mt], bfh, acc[mt][nt], 0, 0, 0);
      }
    }
  }

#pragma unroll
  for (int mt = 0; mt < 4; ++mt) {
    float scalev[4] = {1.f, 1.f, 1.f, 1.f};
    if constexpr (L2N) {
#pragma unroll
      for (int rr = 0; rr < 4; ++rr) {
        float ss = 0.f;
#pragma unroll
        for (int nt = 0; nt < 4; ++nt) ss += acc[mt][nt][rr] * acc[mt][nt][rr];
        ss += __shfl_xor(ss, 1, 64);
        ss += __shfl_xor(ss, 2, 64);
        ss += __shfl_xor(ss, 4, 64);
        ss += __shfl_xor(ss, 8, 64);
        scalev[rr] = 1.0f / fmaxf(sqrtf(ss), 1e-12f);
      }
    }
#pragma unroll
    for (int nt = 0; nt < 4; ++nt) {
#pragma unroll
      for (int rr = 0; rr < 4; ++rr) {
        const int row = m0 + wm * 64 + mt * 16 + quad * 4 + rr;
        const int col = n0 + wn * 64 + nt * 16 + n15;
        const float v = acc[mt][nt][rr] * scalev[rr];
        if constexpr (F32OUT)
          ((float*)Cv)[(size_t)row * N + col] = v;
        else
          ((unsigned short*)Cv)[(size_t)row * N + col] = f2bf(v);
      }
    }
  }
}

// ---------------------------------------------------------------------------
// Fused q-proj + k-proj + v-proj, one launch (864 blocks) with XCD swizzle:
// logical id bi = (bid&7)*108 + (bid>>3)  (bijective: 864 = 8*108), so each
// XCD gets 108 consecutive logical blocks -> blocks sharing A/B panels
// co-reside on one L2 (R6-measured mechanism: attn FETCH 99.9->15.4 MB).
// [0,96) q (BSPLIT+L2N) | [96,480) k (BSPLIT+L2N) | [480,864) v (plain).
// ---------------------------------------------------------------------------
__global__ __launch_bounds__(256) void qkv_proj(
    const unsigned short* __restrict__ x1h,
    const unsigned short* __restrict__ Wqh, const unsigned short* __restrict__ Wql,
    const unsigned short* __restrict__ x2h,
    const unsigned short* __restrict__ Wkh, const unsigned short* __restrict__ Wkl,
    const unsigned short* __restrict__ Wvh,
    unsigned short* __restrict__ qbf, unsigned short* __restrict__ kbf,
    unsigned short* __restrict__ vtbf) {
  __shared__ __align__(16) unsigned short sAh[4096], sBh[4096], sBl[4096];
  const int bid = blockIdx.x;
  const int bi = (bid & 7) * 108 + (bid >> 3);
  if (bi < 96) {
    gemm_tile<true, true, false>(x1h, Wqh, Wql, qbf, B1, DMODEL, DMODEL,
                                 (bi / 6) * 128, (bi % 6) * 128, sAh, sBh, sBl);
  } else if (bi < 480) {
    const int b = bi - 96;
    gemm_tile<true, true, false>(x2h, Wkh, Wkl, kbf, B2, DMODEL, DMODEL,
                                 (b / 6) * 128, (b % 6) * 128, sAh, sBh, sBl);
  } else {
    const int b = bi - 480;
    gemm_tile<false, false, false>(Wvh, x2h, nullptr, vtbf, DMODEL, B2, DMODEL,
                                   (b / 64) * 128, (b % 64) * 128, sAh, sBh, sBl);
  }
}

// ---------------------------------------------------------------------------
// MFMA bf16 attention — R8-verified structure (unchanged):
//  - K LDS double-buffered, ONE barrier per chunk; K prefetch 2 chunks deep.
//  - V loads hoisted to chunk start into regs, consumed by same-chunk PV.
//  - Ps wave-private LDS round trip; slab plain stores; XCD swizzle;
//    KSPLIT=2.
// ---------------------------------------------------------------------------
#define KC 128
#define KSPLIT 2
#define NCH (B2 / KSPLIT / KC)  // 32
#define PSTR 68

__global__ __launch_bounds__(256, 3) void attn_mfma(
    const unsigned short* __restrict__ qb, const unsigned short* __restrict__ kb,
    const unsigned short* __restrict__ vt, float* __restrict__ aoacc,
    float* __restrict__ lacc, const int* __restrict__ invt_p) {
  __shared__ __align__(16) unsigned short smem[25088];  // 50176 B
  // Kl dbuf: [2][128 keys][64 dims] at smem+0 / smem+8192 (shorts)
  unsigned short* Psl = smem + 16384;   // 4 waves x 32 x PSTR

  const int bid = blockIdx.x;                     // 0..767
  const int swz = (bid & 7) * 96 + (bid >> 3);    // bijective (768 % 8 == 0)
  const int zz = swz / 384;
  const int rem = swz - zz * 384;
  const int h = rem >> 5;
  const int q0 = (rem & 31) * 64;

  const float c2 = (float)invt_p[0] * 1.4426950408889634f;
  const int tid = threadIdx.x;
  const int wave = tid >> 6;
  const int lane = tid & 63;
  const int qsub = wave >> 1;
  const int ksub = wave & 1;
  const int n15 = lane & 15;
  const int quad = lane >> 4;
  const int kz0 = zz * (B2 / KSPLIT);

  unsigned short* Ps = &Psl[wave * 32 * PSTR];

  short8 qf[2][2];
#pragma unroll
  for (int qt = 0; qt < 2; ++qt)
#pragma unroll
    for (int ks = 0; ks < 2; ++ks) {
      const int qrow = q0 + qsub * 32 + qt * 16 + n15;
      qf[qt][ks] = *(const short8*)&qb[(size_t)qrow * DMODEL + h * DH + ks * 32 + quad * 8];
    }

  floatx4 oacc[2][4];
#pragma unroll
  for (int qt = 0; qt < 2; ++qt)
#pragma unroll
    for (int nt = 0; nt < 4; ++nt) oacc[qt][nt] = (floatx4){0.f, 0.f, 0.f, 0.f};
  float lsum[2] = {0.f, 0.f};

  const unsigned short* kbp = kb + (size_t)kz0 * DMODEL + h * DH;
  const unsigned short* vbp = vt + (size_t)(h * DH) * B2 + kz0;

  // prologue: load K chunk0 -> stage buf0 -> load K chunk1 -> barrier
  ushort8 kr[4];
#pragma unroll
  for (int i = 0; i < 4; ++i) {
    const int s = i * 256 + tid;
    const int key = s >> 3, cpk = s & 7, chk = cpk ^ (key & 7);
    kr[i] = *(const ushort8*)&kbp[(size_t)key * DMODEL + chk * 8];
  }
#pragma unroll
  for (int i = 0; i < 4; ++i) {
    const int s = i * 256 + tid;
    const int key = s >> 3, cpk = s & 7;
    *(ushort8*)&smem[key * 64 + cpk * 8] = kr[i];
  }
#pragma unroll
  for (int i = 0; i < 4; ++i) {
    const int s = i * 256 + tid;
    const int key = s >> 3, cpk = s & 7, chk = cpk ^ (key & 7);
    kr[i] = *(const ushort8*)&kbp[(size_t)(KC + key) * DMODEL + chk * 8];
  }
  __syncthreads();

  for (int c = 0; c < NCH; ++c) {
    unsigned short* Kb = &smem[(c & 1) * 8192];
    unsigned short* Kn = &smem[((c + 1) & 1) * 8192];
    const unsigned short* vc_ = vbp + c * KC;

    // early V issue for THIS chunk (consumed in PV below)
    ushort8 vr[8];
#pragma unroll
    for (int ks = 0; ks < 2; ++ks)
#pragma unroll
      for (int nt = 0; nt < 4; ++nt)
        vr[ks * 4 + nt] = *(const ushort8*)&vc_[
            (size_t)(nt * 16 + n15) * B2 + (ksub * 8 + ks * 4 + quad) * 8];

    // stage chunk c+1 into the other buffer; load chunk c+2
    if (c + 1 < NCH) {
#pragma unroll
      for (int i = 0; i < 4; ++i) {
        const int s = i * 256 + tid;
        const int key = s >> 3, cpk = s & 7;
        *(ushort8*)&Kn[key * 64 + cpk * 8] = kr[i];
      }
      if (c + 2 < NCH) {
        const unsigned short* k2 = kbp + (size_t)(c + 2) * KC * DMODEL;
#pragma unroll
        for (int i = 0; i < 4; ++i) {
          const int s = i * 256 + tid;
          const int key = s >> 3, cpk = s & 7, chk = cpk ^ (key & 7);
          kr[i] = *(const ushort8*)&k2[(size_t)key * DMODEL + chk * 8];
        }
      }
    }

    // ---- QK^T from Kb ----
#pragma unroll
    for (int kt = 0; kt < 4; ++kt) {
      floatx4 s0 = {0.f, 0.f, 0.f, 0.f}, s1 = {0.f, 0.f, 0.f, 0.f};
#pragma unroll
      for (int ks = 0; ks < 2; ++ks) {
        const int key = ksub * 64 + kt * 16 + n15;
        const int cp = (ks * 4 + quad) ^ (n15 & 7);
        const short8 kf = *(const short8*)&Kb[key * 64 + cp * 8];
        s0 = __builtin_amdgcn_mfma_f32_16x16x32_bf16(kf, qf[0][ks], s0, 0, 0, 0);
        s1 = __builtin_amdgcn_mfma_f32_16x16x32_bf16(kf, qf[1][ks], s1, 0, 0, 0);
      }
      ushort4v p0, p1;
#pragma unroll
      for (int r = 0; r < 4; ++r) {
        const float e0 = exp2f(fmaf(s0[r], c2, -c2));
        const float e1 = exp2f(fmaf(s1[r], c2, -c2));
        lsum[0] += e0;
        lsum[1] += e1;
        p0[r] = f2bf(e0);
        p1[r] = f2bf(e1);
      }
      *(ushort4v*)&Ps[(0 * 16 + n15) * PSTR + kt * 16 + quad * 4] = p0;
      *(ushort4v*)&Ps[(1 * 16 + n15) * PSTR + kt * 16 + quad * 4] = p1;
    }

    // ---- PV using prefetched vr ----
#pragma unroll
    for (int ks = 0; ks < 2; ++ks) {
      short8 pa[2];
#pragma unroll
      for (int qt = 0; qt < 2; ++qt)
        pa[qt] = *(const short8*)&Ps[(qt * 16 + n15) * PSTR + ks * 32 + quad * 8];
#pragma unroll
      for (int nt = 0; nt < 4; ++nt) {
        const short8 vf = __builtin_bit_cast(short8, vr[ks * 4 + nt]);
        oacc[0][nt] = __builtin_amdgcn_mfma_f32_16x16x32_bf16(pa[0], vf, oacc[0][nt], 0, 0, 0);
        oacc[1][nt] = __builtin_amdgcn_mfma_f32_16x16x32_bf16(pa[1], vf, oacc[1][nt], 0, 0, 0);
      }
    }

    __syncthreads();  // publish Kn; prior Kb readers done before next overwrite
  }

#pragma unroll
  for (int qt = 0; qt < 2; ++qt) {
    float v = lsum[qt];
    v += __shfl_xor(v, 16, 64);
    v += __shfl_xor(v, 32, 64);
    lsum[qt] = v;
  }

  float* aoz = aoacc + (size_t)zz * B1 * DMODEL;
  float* lz = lacc + (size_t)zz * B1 * NH;

  __syncthreads();
  float* Osc = (float*)smem;        // [64 q][64 d] f32 = 16384 B
  float* lsc = Osc + 4096;          // [64 q] f32 (total 16640 <= 50176)
  if (ksub == 1) {
#pragma unroll
    for (int qt = 0; qt < 2; ++qt)
#pragma unroll
      for (int nt = 0; nt < 4; ++nt)
#pragma unroll
        for (int r = 0; r < 4; ++r) {
          const int row = qsub * 32 + qt * 16 + quad * 4 + r;
          Osc[row * 64 + nt * 16 + n15] = oacc[qt][nt][r];
        }
    if (quad == 0) {
      lsc[qsub * 32 + n15] = lsum[0];
      lsc[qsub * 32 + 16 + n15] = lsum[1];
    }
  }
  __syncthreads();
  if (ksub == 0) {
#pragma unroll
    for (int qt = 0; qt < 2; ++qt)
#pragma unroll
      for (int nt = 0; nt < 4; ++nt)
#pragma unroll
        for (int r = 0; r < 4; ++r) {
          const int row = qsub * 32 + qt * 16 + quad * 4 + r;
          const float v = oacc[qt][nt][r] + Osc[row * 64 + nt * 16 + n15];
          aoz[(size_t)(q0 + row) * DMODEL + h * DH + nt * 16 + n15] = v;
        }
    if (quad == 0) {
      lz[(size_t)(q0 + qsub * 32 + n15) * NH + h] = lsum[0] + lsc[qsub * 32 + n15];
      lz[(size_t)(q0 + qsub * 32 + 16 + n15) * NH + h] =
          lsum[1] + lsc[qsub * 32 + 16 + n15];
    }
  }
}

// ---------------------------------------------------------------------------
// Wo projection with FUSED slab-sum + ao-normalize in A-staging, XCD swizzle
// (96 = 8*12: each XCD gets 12 consecutive logical blocks = 2 m-tiles, so
// the 6 n-blocks sharing an A-slab panel co-reside on one L2).
// A[row][col] = bf16( (ao0+ao1)[row][col] / (l0+l1)[row][col>>6] ).
// B = Woh (gload16). C = f32 woout [B1, 768]. 96 blocks.
// ---------------------------------------------------------------------------
__global__ __launch_bounds__(256) void wo_proj(
    const float* __restrict__ aoacc, const float* __restrict__ lacc,
    const unsigned short* __restrict__ Woh, float* __restrict__ woout) {
  __shared__ __align__(16) unsigned short sAh[4096], sBh[4096];
  const int bid = blockIdx.x;
  const int bi = (bid & 7) * 12 + (bid >> 3);
  const int m0 = (bi / 6) * 128;
  const int n0 = (bi % 6) * 128;
  const int tid = threadIdx.x;
  const int wave = tid >> 6;
  const int lane = tid & 63;
  const int wm = wave >> 1;
  const int wn = wave & 1;
  const int n15 = lane & 15;
  const int quad = lane >> 4;
  const int srow = lane >> 2;
  const int cpl = (lane & 3) ^ (srow >> 2);

  const float* ao1 = aoacc + (size_t)B1 * DMODEL;
  const float* la1 = lacc + (size_t)B1 * NH;

  floatx4 acc[4][4];
#pragma unroll
  for (int i = 0; i < 4; ++i)
#pragma unroll
    for (int j = 0; j < 4; ++j) acc[i][j] = (floatx4){0.f, 0.f, 0.f, 0.f};

  for (int k0 = 0; k0 < DMODEL; k0 += 32) {
    __syncthreads();
#pragma unroll
    for (int jj = 0; jj < 2; ++jj) {
      const int j = wave * 2 + jj;
      const int row = j * 16 + srow;
      // A: load 8 f32 from each slab, sum, normalize, convert, ds_write 16B
      const size_t ga = (size_t)(m0 + row) * DMODEL + k0 + cpl * 8;
      const float4 a0 = *(const float4*)&aoacc[ga];
      const float4 a1 = *(const float4*)&aoacc[ga + 4];
      const float4 b0 = *(const float4*)&ao1[ga];
      const float4 b1 = *(const float4*)&ao1[ga + 4];
      const int head = (k0 + cpl * 8) >> 6;
      const float lsum = lacc[(m0 + row) * NH + head] + la1[(m0 + row) * NH + head];
      const float inv = 1.0f / lsum;
      ushort8 ah = {f2bf((a0.x + b0.x) * inv), f2bf((a0.y + b0.y) * inv),
                    f2bf((a0.z + b0.z) * inv), f2bf((a0.w + b0.w) * inv),
                    f2bf((a1.x + b1.x) * inv), f2bf((a1.y + b1.y) * inv),
                    f2bf((a1.z + b1.z) * inv), f2bf((a1.w + b1.w) * inv)};
      *(ushort8*)&sAh[j * 512 + lane * 8] = ah;
      // B: async staging
      gload16(Woh + (size_t)(n0 + row) * DMODEL + k0 + cpl * 8, &sBh[j * 512]);
    }
    __syncthreads();

    short8 afh[4];
#pragma unroll
    for (int mt = 0; mt < 4; ++mt) {
      const int row = wm * 64 + mt * 16 + n15;
      afh[mt] = *(const short8*)&sAh[row * 32 + ((quad ^ (n15 >> 2)) << 3)];
    }
#pragma unroll
    for (int nt = 0; nt < 4; ++nt) {
      const int row = wn * 64 + nt * 16 + n15;
      const short8 bfh = *(const short8*)&sBh[row * 32 + ((quad ^ (n15 >> 2)) << 3)];
#pragma unroll
      for (int mt = 0; mt < 4; ++mt)
        acc[mt][nt] = __builtin_amdgcn_mfma_f32_16x16x32_bf16(afh[mt], bfh, acc[mt][nt], 0, 0, 0);
    }
  }

#pragma unroll
  for (int mt = 0; mt < 4; ++mt)
#pragma unroll
    for (int nt = 0; nt < 4; ++nt)
#pragma unroll
      for (int rr = 0; rr < 4; ++rr) {
        const int row = m0 + wm * 64 + mt * 16 + quad * 4 + rr;
        const int col = n0 + wn * 64 + nt * 16 + n15;
        woout[(size_t)row * DMODEL + col] = acc[mt][nt][rr];
      }
}

// ---------------------------------------------------------------------------
__global__ __launch_bounds__(256) void l2norm_rows768_out(
    const float* __restrict__ x, float* __restrict__ out) {
  const int row = blockIdx.x;
  const float* xr = &x[(size_t)row * DMODEL];
  float ss = 0.0f;
  float vals[3];
#pragma unroll
  for (int i = 0; i < 3; ++i) {
    vals[i] = xr[threadIdx.x + i * 256];
    ss += vals[i] * vals[i];
  }
#pragma unroll
  for (int off = 32; off > 0; off >>= 1) ss += __shfl_xor(ss, off, 64);
  __shared__ float ws[4];
  if ((threadIdx.x & 63) == 0) ws[threadIdx.x >> 6] = ss;
  __syncthreads();
  const float tot = ws[0] + ws[1] + ws[2] + ws[3];
  const float sc = 1.0f / fmaxf(sqrtf(tot), 1e-12f);
  float* orow = &out[(size_t)row * DMODEL];
#pragma unroll
  for (int i = 0; i < 3; ++i) orow[threadIdx.x + i * 256] = vals[i] * sc;
}

// ---------------------------------------------------------------------------
extern "C" void kernel_launch(void* const* d_in, const int* in_sizes, int n_in,
                              void* d_out, int out_size, void* d_ws,
                              size_t ws_size, hipStream_t stream) {
  const float* x1 = (const float*)d_in[0];
  const float* x2 = (const float*)d_in[1];
  const float* Wq = (const float*)d_in[2];
  const float* Wk = (const float*)d_in[3];
  const float* Wv = (const float*)d_in[4];
  const float* Wo = (const float*)d_in[5];
  const int* invt = (const int*)d_in[6];
  float* outp = (float*)d_out;

  // workspace (bytes). Aliases are lifetime-safe under stream serialization:
  //  aoacc slab0 <- x1h region + pad (x1h dead after qkv)   [0,        6291456)
  //  aoacc slab1 <- x2h first half (dead after qkv)         [6291456, 12582912)
  //  woout       <- x2h second half (dead after qkv)        [12582912,18874368)
  //  vt_bf       <- old x2l region (unused now)             [18874368,31457280)
  //  lacc slabs  <- Wql-adjacent scratch (dead after qkv)   [32636928,32833536)
  char* ws = (char*)d_ws;
  unsigned short* x1h = (unsigned short*)(ws + 0);
  unsigned short* x2h = (unsigned short*)(ws + 6291456);
  unsigned short* Wqh = (unsigned short*)(ws + 31457280);
  unsigned short* Wql = (unsigned short*)(ws + 32636928);
  unsigned short* Wkh = (unsigned short*)(ws + 33816576);
  unsigned short* Wkl = (unsigned short*)(ws + 34996224);
  unsigned short* Wvh = (unsigned short*)(ws + 36175872);
  unsigned short* Woh = (unsigned short*)(ws + 37355520);
  unsigned short* q_bf = (unsigned short*)(ws + 38535168);
  unsigned short* k_bf = (unsigned short*)(ws + 41680896);   // end 54263808
  // aliases:
  float* aoacc = (float*)(ws + 0);                  // 2 slabs, 12582912 B
  float* lacc = (float*)(ws + 32636928);            // 2 slabs over Wql region
  unsigned short* vt_bf = (unsigned short*)(ws + 18874368);
  float* woout = (float*)(ws + 12582912);

  // 1) prep (x1/x2 hi-only; Wq/Wk hi+lo; Wv/Wo hi)
  prep_all<<<9984, 256, 0, stream>>>(x1, x1h, x2, x2h, Wq, Wqh, Wql,
                                     Wk, Wkh, Wkl, Wv, Wvh, Wo, Woh);
  // 2) q+k+v projections fused, one launch, XCD-swizzled
  qkv_proj<<<864, 256, 0, stream>>>(x1h, Wqh, Wql, x2h, Wkh, Wkl, Wvh,
                                    q_bf, k_bf, vt_bf);
  // 3) attention (R8-verified pipeline, unchanged)
  attn_mfma<<<768, 256, 0, stream>>>(q_bf, k_bf, vt_bf, aoacc, lacc, invt);
  // 4) Wo projection with fused slab-sum + ao-normalize staging, XCD-swizzled
  wo_proj<<<96, 256, 0, stream>>>(aoacc, lacc, Woh, woout);
  // 5) final row l2norm
  l2norm_rows768_out<<<B1, 256, 0, stream>>>(woout, outp);
}

// Round 11
// 292.316 us; speedup vs baseline: 1.0350x; 1.0350x over previous
//
#include <hip/hip_runtime.h>
#include <hip/hip_bf16.h>
#include <math.h>

#define B1 2048
#define B2 8192
#define NH 12
#define DH 64
#define DMODEL 768

typedef __attribute__((ext_vector_type(8))) short short8;
typedef __attribute__((ext_vector_type(4))) float floatx4;
typedef __attribute__((ext_vector_type(8))) unsigned short ushort8;
typedef __attribute__((ext_vector_type(4))) unsigned short ushort4v;

static __device__ __forceinline__ unsigned short f2bf(float f) {
  __bf16 b = (__bf16)f;
  return __builtin_bit_cast(unsigned short, b);
}
static __device__ __forceinline__ float bf2f(unsigned short u) {
  return __builtin_bit_cast(float, ((unsigned)u) << 16);
}

// async global->LDS, 16B per lane; LDS dest = wave-uniform base + lane*16
static __device__ __forceinline__ void gload16(const unsigned short* g,
                                               unsigned short* l) {
  __builtin_amdgcn_global_load_lds(
      (const __attribute__((address_space(1))) void*)g,
      (__attribute__((address_space(3))) void*)l, 16, 0, 0);
}

// ---------------------------------------------------------------------------
// Fused prep: fp32 -> bf16, hi-only for ALL tensors (precision ladder:
// R9 showed GEMM-internal residual terms are second-order vs the
// unavoidable downstream bf16 roundings of q_bf/k_bf/P/V).
// block-role table: [0,1536) x1 | [1536,7680) x2 | [7680,8256) Wq |
// [8256,8832) Wk | [8832,9408) Wv | [9408,9984) Wo
// ---------------------------------------------------------------------------
__global__ __launch_bounds__(256) void prep_all(
    const float* __restrict__ x1, unsigned short* __restrict__ x1h,
    const float* __restrict__ x2, unsigned short* __restrict__ x2h,
    const float* __restrict__ Wq, unsigned short* __restrict__ Wqh,
    const float* __restrict__ Wk, unsigned short* __restrict__ Wkh,
    const float* __restrict__ Wv, unsigned short* __restrict__ Wvh,
    const float* __restrict__ Wo, unsigned short* __restrict__ Woh) {
  const int bi = blockIdx.x;
  const float* src;
  unsigned short* hi;
  int lb;
  if (bi < 1536) {
    src = x1; hi = x1h; lb = bi;
  } else if (bi < 7680) {
    src = x2; hi = x2h; lb = bi - 1536;
  } else if (bi < 8256) {
    src = Wq; hi = Wqh; lb = bi - 7680;
  } else if (bi < 8832) {
    src = Wk; hi = Wkh; lb = bi - 8256;
  } else if (bi < 9408) {
    src = Wv; hi = Wvh; lb = bi - 8832;
  } else {
    src = Wo; hi = Woh; lb = bi - 9408;
  }
  const int i = (lb * 256 + threadIdx.x) * 4;
  const float4 v = *(const float4*)&src[i];
  ushort4v h = {f2bf(v.x), f2bf(v.y), f2bf(v.z), f2bf(v.w)};
  *(ushort4v*)&hi[i] = h;
}

// ---------------------------------------------------------------------------
// Core bf16 MFMA GEMM tile: C[M,N] = A[M,K]*B[N,K]^T (both K-contiguous).
// 128x128 tile, BK=32, 4 waves (2x2), 64x64/wave, global_load_lds staging,
// XOR-swizzled granules. L2N: per-64-col L2 norm epilogue.
// ---------------------------------------------------------------------------
template <bool L2N, bool F32OUT>
static __device__ __forceinline__ void gemm_tile(
    const unsigned short* __restrict__ Ahg,
    const unsigned short* __restrict__ Bhg,
    void* __restrict__ Cv, int M, int N, int K, int m0, int n0,
    unsigned short* sAh, unsigned short* sBh) {
  const int tid = threadIdx.x;
  const int wave = tid >> 6;
  const int lane = tid & 63;
  const int wm = wave >> 1;
  const int wn = wave & 1;
  const int n15 = lane & 15;
  const int quad = lane >> 4;
  const int srow = lane >> 2;
  const int cpl = (lane & 3) ^ (srow >> 2);

  floatx4 acc[4][4];
#pragma unroll
  for (int i = 0; i < 4; ++i)
#pragma unroll
    for (int j = 0; j < 4; ++j) acc[i][j] = (floatx4){0.f, 0.f, 0.f, 0.f};

  for (int k0 = 0; k0 < K; k0 += 32) {
    __syncthreads();
#pragma unroll
    for (int jj = 0; jj < 2; ++jj) {
      const int j = wave * 2 + jj;
      const int row = j * 16 + srow;
      const size_t goffA = (size_t)(m0 + row) * K + k0 + cpl * 8;
      const size_t goffB = (size_t)(n0 + row) * K + k0 + cpl * 8;
      gload16(Ahg + goffA, &sAh[j * 512]);
      gload16(Bhg + goffB, &sBh[j * 512]);
    }
    __syncthreads();

    short8 afh[4];
#pragma unroll
    for (int mt = 0; mt < 4; ++mt) {
      const int row = wm * 64 + mt * 16 + n15;
      const int off = row * 32 + ((quad ^ (n15 >> 2)) << 3);
      afh[mt] = *(const short8*)&sAh[off];
    }
#pragma unroll
    for (int nt = 0; nt < 4; ++nt) {
      const int row = wn * 64 + nt * 16 + n15;
      const int off = row * 32 + ((quad ^ (n15 >> 2)) << 3);
      const short8 bfh = *(const short8*)&sBh[off];
#pragma unroll
      for (int mt = 0; mt < 4; ++mt)
        acc[mt][nt] = __builtin_amdgcn_mfma_f32_16x16x32_bf16(afh[mt], bfh, acc[mt][nt], 0, 0, 0);
    }
  }

#pragma unroll
  for (int mt = 0; mt < 4; ++mt) {
    float scalev[4] = {1.f, 1.f, 1.f, 1.f};
    if constexpr (L2N) {
#pragma unroll
      for (int rr = 0; rr < 4; ++rr) {
        float ss = 0.f;
#pragma unroll
        for (int nt = 0; nt < 4; ++nt) ss += acc[mt][nt][rr] * acc[mt][nt][rr];
        ss += __shfl_xor(ss, 1, 64);
        ss += __shfl_xor(ss, 2, 64);
        ss += __shfl_xor(ss, 4, 64);
        ss += __shfl_xor(ss, 8, 64);
        scalev[rr] = 1.0f / fmaxf(sqrtf(ss), 1e-12f);
      }
    }
#pragma unroll
    for (int nt = 0; nt < 4; ++nt) {
#pragma unroll
      for (int rr = 0; rr < 4; ++rr) {
        const int row = m0 + wm * 64 + mt * 16 + quad * 4 + rr;
        const int col = n0 + wn * 64 + nt * 16 + n15;
        const float v = acc[mt][nt][rr] * scalev[rr];
        if constexpr (F32OUT)
          ((float*)Cv)[(size_t)row * N + col] = v;
        else
          ((unsigned short*)Cv)[(size_t)row * N + col] = f2bf(v);
      }
    }
  }
}

// ---------------------------------------------------------------------------
// Fused q-proj + k-proj + v-proj, one launch (864 blocks), plain bf16:
// [0,96) q (L2N) | [96,480) k (L2N) | [480,864) v. No XCD swizzle (R10
// showed whole-launch swizzle segregates block types -> XCD imbalance).
// ---------------------------------------------------------------------------
__global__ __launch_bounds__(256) void qkv_proj(
    const unsigned short* __restrict__ x1h,
    const unsigned short* __restrict__ Wqh,
    const unsigned short* __restrict__ x2h,
    const unsigned short* __restrict__ Wkh,
    const unsigned short* __restrict__ Wvh,
    unsigned short* __restrict__ qbf, unsigned short* __restrict__ kbf,
    unsigned short* __restrict__ vtbf) {
  __shared__ __align__(16) unsigned short sAh[4096], sBh[4096];
  const int bi = blockIdx.x;
  if (bi < 96) {
    gemm_tile<true, false>(x1h, Wqh, qbf, B1, DMODEL, DMODEL,
                           (bi / 6) * 128, (bi % 6) * 128, sAh, sBh);
  } else if (bi < 480) {
    const int b = bi - 96;
    gemm_tile<true, false>(x2h, Wkh, kbf, B2, DMODEL, DMODEL,
                           (b / 6) * 128, (b % 6) * 128, sAh, sBh);
  } else {
    const int b = bi - 480;
    gemm_tile<false, false>(Wvh, x2h, vtbf, DMODEL, B2, DMODEL,
                            (b / 64) * 128, (b % 64) * 128, sAh, sBh);
  }
}

// ---------------------------------------------------------------------------
// MFMA bf16 attention — R8-verified structure (unchanged):
//  - K LDS double-buffered, ONE barrier per chunk; K prefetch 2 chunks deep.
//  - V loads hoisted to chunk start into regs, consumed by same-chunk PV.
//  - Ps wave-private LDS round trip; slab plain stores; XCD swizzle;
//    KSPLIT=2.
// ---------------------------------------------------------------------------
#define KC 128
#define KSPLIT 2
#define NCH (B2 / KSPLIT / KC)  // 32
#define PSTR 68

__global__ __launch_bounds__(256, 3) void attn_mfma(
    const unsigned short* __restrict__ qb, const unsigned short* __restrict__ kb,
    const unsigned short* __restrict__ vt, float* __restrict__ aoacc,
    float* __restrict__ lacc, const int* __restrict__ invt_p) {
  __shared__ __align__(16) unsigned short smem[25088];  // 50176 B
  // Kl dbuf: [2][128 keys][64 dims] at smem+0 / smem+8192 (shorts)
  unsigned short* Psl = smem + 16384;   // 4 waves x 32 x PSTR

  const int bid = blockIdx.x;                     // 0..767
  const int swz = (bid & 7) * 96 + (bid >> 3);    // bijective (768 % 8 == 0)
  const int zz = swz / 384;
  const int rem = swz - zz * 384;
  const int h = rem >> 5;
  const int q0 = (rem & 31) * 64;

  const float c2 = (float)invt_p[0] * 1.4426950408889634f;
  const int tid = threadIdx.x;
  const int wave = tid >> 6;
  const int lane = tid & 63;
  const int qsub = wave >> 1;
  const int ksub = wave & 1;
  const int n15 = lane & 15;
  const int quad = lane >> 4;
  const int kz0 = zz * (B2 / KSPLIT);

  unsigned short* Ps = &Psl[wave * 32 * PSTR];

  short8 qf[2][2];
#pragma unroll
  for (int qt = 0; qt < 2; ++qt)
#pragma unroll
    for (int ks = 0; ks < 2; ++ks) {
      const int qrow = q0 + qsub * 32 + qt * 16 + n15;
      qf[qt][ks] = *(const short8*)&qb[(size_t)qrow * DMODEL + h * DH + ks * 32 + quad * 8];
    }

  floatx4 oacc[2][4];
#pragma unroll
  for (int qt = 0; qt < 2; ++qt)
#pragma unroll
    for (int nt = 0; nt < 4; ++nt) oacc[qt][nt] = (floatx4){0.f, 0.f, 0.f, 0.f};
  float lsum[2] = {0.f, 0.f};

  const unsigned short* kbp = kb + (size_t)kz0 * DMODEL + h * DH;
  const unsigned short* vbp = vt + (size_t)(h * DH) * B2 + kz0;

  // prologue: load K chunk0 -> stage buf0 -> load K chunk1 -> barrier
  ushort8 kr[4];
#pragma unroll
  for (int i = 0; i < 4; ++i) {
    const int s = i * 256 + tid;
    const int key = s >> 3, cpk = s & 7, chk = cpk ^ (key & 7);
    kr[i] = *(const ushort8*)&kbp[(size_t)key * DMODEL + chk * 8];
  }
#pragma unroll
  for (int i = 0; i < 4; ++i) {
    const int s = i * 256 + tid;
    const int key = s >> 3, cpk = s & 7;
    *(ushort8*)&smem[key * 64 + cpk * 8] = kr[i];
  }
#pragma unroll
  for (int i = 0; i < 4; ++i) {
    const int s = i * 256 + tid;
    const int key = s >> 3, cpk = s & 7, chk = cpk ^ (key & 7);
    kr[i] = *(const ushort8*)&kbp[(size_t)(KC + key) * DMODEL + chk * 8];
  }
  __syncthreads();

  for (int c = 0; c < NCH; ++c) {
    unsigned short* Kb = &smem[(c & 1) * 8192];
    unsigned short* Kn = &smem[((c + 1) & 1) * 8192];
    const unsigned short* vc_ = vbp + c * KC;

    // early V issue for THIS chunk (consumed in PV below)
    ushort8 vr[8];
#pragma unroll
    for (int ks = 0; ks < 2; ++ks)
#pragma unroll
      for (int nt = 0; nt < 4; ++nt)
        vr[ks * 4 + nt] = *(const ushort8*)&vc_[
            (size_t)(nt * 16 + n15) * B2 + (ksub * 8 + ks * 4 + quad) * 8];

    // stage chunk c+1 into the other buffer; load chunk c+2
    if (c + 1 < NCH) {
#pragma unroll
      for (int i = 0; i < 4; ++i) {
        const int s = i * 256 + tid;
        const int key = s >> 3, cpk = s & 7;
        *(ushort8*)&Kn[key * 64 + cpk * 8] = kr[i];
      }
      if (c + 2 < NCH) {
        const unsigned short* k2 = kbp + (size_t)(c + 2) * KC * DMODEL;
#pragma unroll
        for (int i = 0; i < 4; ++i) {
          const int s = i * 256 + tid;
          const int key = s >> 3, cpk = s & 7, chk = cpk ^ (key & 7);
          kr[i] = *(const ushort8*)&k2[(size_t)key * DMODEL + chk * 8];
        }
      }
    }

    // ---- QK^T from Kb ----
#pragma unroll
    for (int kt = 0; kt < 4; ++kt) {
      floatx4 s0 = {0.f, 0.f, 0.f, 0.f}, s1 = {0.f, 0.f, 0.f, 0.f};
#pragma unroll
      for (int ks = 0; ks < 2; ++ks) {
        const int key = ksub * 64 + kt * 16 + n15;
        const int cp = (ks * 4 + quad) ^ (n15 & 7);
        const short8 kf = *(const short8*)&Kb[key * 64 + cp * 8];
        s0 = __builtin_amdgcn_mfma_f32_16x16x32_bf16(kf, qf[0][ks], s0, 0, 0, 0);
        s1 = __builtin_amdgcn_mfma_f32_16x16x32_bf16(kf, qf[1][ks], s1, 0, 0, 0);
      }
      ushort4v p0, p1;
#pragma unroll
      for (int r = 0; r < 4; ++r) {
        const float e0 = exp2f(fmaf(s0[r], c2, -c2));
        const float e1 = exp2f(fmaf(s1[r], c2, -c2));
        lsum[0] += e0;
        lsum[1] += e1;
        p0[r] = f2bf(e0);
        p1[r] = f2bf(e1);
      }
      *(ushort4v*)&Ps[(0 * 16 + n15) * PSTR + kt * 16 + quad * 4] = p0;
      *(ushort4v*)&Ps[(1 * 16 + n15) * PSTR + kt * 16 + quad * 4] = p1;
    }

    // ---- PV using prefetched vr ----
#pragma unroll
    for (int ks = 0; ks < 2; ++ks) {
      short8 pa[2];
#pragma unroll
      for (int qt = 0; qt < 2; ++qt)
        pa[qt] = *(const short8*)&Ps[(qt * 16 + n15) * PSTR + ks * 32 + quad * 8];
#pragma unroll
      for (int nt = 0; nt < 4; ++nt) {
        const short8 vf = __builtin_bit_cast(short8, vr[ks * 4 + nt]);
        oacc[0][nt] = __builtin_amdgcn_mfma_f32_16x16x32_bf16(pa[0], vf, oacc[0][nt], 0, 0, 0);
        oacc[1][nt] = __builtin_amdgcn_mfma_f32_16x16x32_bf16(pa[1], vf, oacc[1][nt], 0, 0, 0);
      }
    }

    __syncthreads();  // publish Kn; prior Kb readers done before next overwrite
  }

#pragma unroll
  for (int qt = 0; qt < 2; ++qt) {
    float v = lsum[qt];
    v += __shfl_xor(v, 16, 64);
    v += __shfl_xor(v, 32, 64);
    lsum[qt] = v;
  }

  float* aoz = aoacc + (size_t)zz * B1 * DMODEL;
  float* lz = lacc + (size_t)zz * B1 * NH;

  __syncthreads();
  float* Osc = (float*)smem;        // [64 q][64 d] f32 = 16384 B
  float* lsc = Osc + 4096;          // [64 q] f32 (total 16640 <= 50176)
  if (ksub == 1) {
#pragma unroll
    for (int qt = 0; qt < 2; ++qt)
#pragma unroll
      for (int nt = 0; nt < 4; ++nt)
#pragma unroll
        for (int r = 0; r < 4; ++r) {
          const int row = qsub * 32 + qt * 16 + quad * 4 + r;
          Osc[row * 64 + nt * 16 + n15] = oacc[qt][nt][r];
        }
    if (quad == 0) {
      lsc[qsub * 32 + n15] = lsum[0];
      lsc[qsub * 32 + 16 + n15] = lsum[1];
    }
  }
  __syncthreads();
  if (ksub == 0) {
#pragma unroll
    for (int qt = 0; qt < 2; ++qt)
#pragma unroll
      for (int nt = 0; nt < 4; ++nt)
#pragma unroll
        for (int r = 0; r < 4; ++r) {
          const int row = qsub * 32 + qt * 16 + quad * 4 + r;
          const float v = oacc[qt][nt][r] + Osc[row * 64 + nt * 16 + n15];
          aoz[(size_t)(q0 + row) * DMODEL + h * DH + nt * 16 + n15] = v;
        }
    if (quad == 0) {
      lz[(size_t)(q0 + qsub * 32 + n15) * NH + h] = lsum[0] + lsc[qsub * 32 + n15];
      lz[(size_t)(q0 + qsub * 32 + 16 + n15) * NH + h] =
          lsum[1] + lsc[qsub * 32 + 16 + n15];
    }
  }
}

// ---------------------------------------------------------------------------
// Wo projection with FUSED slab-sum + ao-normalize in A-staging:
// A[row][col] = bf16( (ao0+ao1)[row][col] / (l0+l1)[row][col>>6] ).
// B = Woh (gload16). C = f32 woout [B1, 768]. 96 blocks. (no swizzle — R10)
// ---------------------------------------------------------------------------
__global__ __launch_bounds__(256) void wo_proj(
    const float* __restrict__ aoacc, const float* __restrict__ lacc,
    const unsigned short* __restrict__ Woh, float* __restrict__ woout) {
  __shared__ __align__(16) unsigned short sAh[4096], sBh[4096];
  const int bi = blockIdx.x;
  const int m0 = (bi / 6) * 128;
  const int n0 = (bi % 6) * 128;
  const int tid = threadIdx.x;
  const int wave = tid >> 6;
  const int lane = tid & 63;
  const int wm = wave >> 1;
  const int wn = wave & 1;
  const int n15 = lane & 15;
  const int quad = lane >> 4;
  const int srow = lane >> 2;
  const int cpl = (lane & 3) ^ (srow >> 2);

  const float* ao1 = aoacc + (size_t)B1 * DMODEL;
  const float* la1 = lacc + (size_t)B1 * NH;

  floatx4 acc[4][4];
#pragma unroll
  for (int i = 0; i < 4; ++i)
#pragma unroll
    for (int j = 0; j < 4; ++j) acc[i][j] = (floatx4){0.f, 0.f, 0.f, 0.f};

  for (int k0 = 0; k0 < DMODEL; k0 += 32) {
    __syncthreads();
#pragma unroll
    for (int jj = 0; jj < 2; ++jj) {
      const int j = wave * 2 + jj;
      const int row = j * 16 + srow;
      // A: load 8 f32 from each slab, sum, normalize, convert, ds_write 16B
      const size_t ga = (size_t)(m0 + row) * DMODEL + k0 + cpl * 8;
      const float4 a0 = *(const float4*)&aoacc[ga];
      const float4 a1 = *(const float4*)&aoacc[ga + 4];
      const float4 b0 = *(const float4*)&ao1[ga];
      const float4 b1 = *(const float4*)&ao1[ga + 4];
      const int head = (k0 + cpl * 8) >> 6;
      const float lsum = lacc[(m0 + row) * NH + head] + la1[(m0 + row) * NH + head];
      const float inv = 1.0f / lsum;
      ushort8 ah = {f2bf((a0.x + b0.x) * inv), f2bf((a0.y + b0.y) * inv),
                    f2bf((a0.z + b0.z) * inv), f2bf((a0.w + b0.w) * inv),
                    f2bf((a1.x + b1.x) * inv), f2bf((a1.y + b1.y) * inv),
                    f2bf((a1.z + b1.z) * inv), f2bf((a1.w + b1.w) * inv)};
      *(ushort8*)&sAh[j * 512 + lane * 8] = ah;
      // B: async staging
      gload16(Woh + (size_t)(n0 + row) * DMODEL + k0 + cpl * 8, &sBh[j * 512]);
    }
    __syncthreads();

    short8 afh[4];
#pragma unroll
    for (int mt = 0; mt < 4; ++mt) {
      const int row = wm * 64 + mt * 16 + n15;
      afh[mt] = *(const short8*)&sAh[row * 32 + ((quad ^ (n15 >> 2)) << 3)];
    }
#pragma unroll
    for (int nt = 0; nt < 4; ++nt) {
      const int row = wn * 64 + nt * 16 + n15;
      const short8 bfh = *(const short8*)&sBh[row * 32 + ((quad ^ (n15 >> 2)) << 3)];
#pragma unroll
      for (int mt = 0; mt < 4; ++mt)
        acc[mt][nt] = __builtin_amdgcn_mfma_f32_16x16x32_bf16(afh[mt], bfh, acc[mt][nt], 0, 0, 0);
    }
  }

#pragma unroll
  for (int mt = 0; mt < 4; ++mt)
#pragma unroll
    for (int nt = 0; nt < 4; ++nt)
#pragma unroll
      for (int rr = 0; rr < 4; ++rr) {
        const int row = m0 + wm * 64 + mt * 16 + quad * 4 + rr;
        const int col = n0 + wn * 64 + nt * 16 + n15;
        woout[(size_t)row * DMODEL + col] = acc[mt][nt][rr];
      }
}

// ---------------------------------------------------------------------------
__global__ __launch_bounds__(256) void l2norm_rows768_out(
    const float* __restrict__ x, float* __restrict__ out) {
  const int row = blockIdx.x;
  const float* xr = &x[(size_t)row * DMODEL];
  float ss = 0.0f;
  float vals[3];
#pragma unroll
  for (int i = 0; i < 3; ++i) {
    vals[i] = xr[threadIdx.x + i * 256];
    ss += vals[i] * vals[i];
  }
#pragma unroll
  for (int off = 32; off > 0; off >>= 1) ss += __shfl_xor(ss, off, 64);
  __shared__ float ws[4];
  if ((threadIdx.x & 63) == 0) ws[threadIdx.x >> 6] = ss;
  __syncthreads();
  const float tot = ws[0] + ws[1] + ws[2] + ws[3];
  const float sc = 1.0f / fmaxf(sqrtf(tot), 1e-12f);
  float* orow = &out[(size_t)row * DMODEL];
#pragma unroll
  for (int i = 0; i < 3; ++i) orow[threadIdx.x + i * 256] = vals[i] * sc;
}

// ---------------------------------------------------------------------------
extern "C" void kernel_launch(void* const* d_in, const int* in_sizes, int n_in,
                              void* d_out, int out_size, void* d_ws,
                              size_t ws_size, hipStream_t stream) {
  const float* x1 = (const float*)d_in[0];
  const float* x2 = (const float*)d_in[1];
  const float* Wq = (const float*)d_in[2];
  const float* Wk = (const float*)d_in[3];
  const float* Wv = (const float*)d_in[4];
  const float* Wo = (const float*)d_in[5];
  const int* invt = (const int*)d_in[6];
  float* outp = (float*)d_out;

  // workspace (bytes). Aliases are lifetime-safe under stream serialization:
  //  aoacc slab0 <- x1h region + pad (x1h dead after qkv)   [0,        6291456)
  //  aoacc slab1 <- x2h first half (dead after qkv)         [6291456, 12582912)
  //  woout       <- x2h second half (dead after qkv)        [12582912,18874368)
  //  vt_bf       <- old x2l region (unused now)             [18874368,31457280)
  //  lacc slabs  <- old Wql region (never written now)      [32636928,32833536)
  char* ws = (char*)d_ws;
  unsigned short* x1h = (unsigned short*)(ws + 0);
  unsigned short* x2h = (unsigned short*)(ws + 6291456);
  unsigned short* Wqh = (unsigned short*)(ws + 31457280);
  unsigned short* Wkh = (unsigned short*)(ws + 33816576);
  unsigned short* Wvh = (unsigned short*)(ws + 36175872);
  unsigned short* Woh = (unsigned short*)(ws + 37355520);
  unsigned short* q_bf = (unsigned short*)(ws + 38535168);
  unsigned short* k_bf = (unsigned short*)(ws + 41680896);   // end 54263808
  // aliases:
  float* aoacc = (float*)(ws + 0);                  // 2 slabs, 12582912 B
  float* lacc = (float*)(ws + 32636928);            // 2 slabs, 196608 B
  unsigned short* vt_bf = (unsigned short*)(ws + 18874368);
  float* woout = (float*)(ws + 12582912);

  // 1) prep (all tensors hi-only bf16)
  prep_all<<<9984, 256, 0, stream>>>(x1, x1h, x2, x2h, Wq, Wqh,
                                     Wk, Wkh, Wv, Wvh, Wo, Woh);
  // 2) q+k+v projections fused, one launch, plain bf16 GEMMs
  qkv_proj<<<864, 256, 0, stream>>>(x1h, Wqh, x2h, Wkh, Wvh,
                                    q_bf, k_bf, vt_bf);
  // 3) attention (R8-verified pipeline, unchanged)
  attn_mfma<<<768, 256, 0, stream>>>(q_bf, k_bf, vt_bf, aoacc, lacc, invt);
  // 4) Wo projection with fused slab-sum + ao-normalize staging
  wo_proj<<<96, 256, 0, stream>>>(aoacc, lacc, Woh, woout);
  // 5) final row l2norm
  l2norm_rows768_out<<<B1, 256, 0, stream>>>(woout, outp);
}

// Round 12
// 291.137 us; speedup vs baseline: 1.0392x; 1.0040x over previous
//
#include <hip/hip_runtime.h>
#include <hip/hip_bf16.h>
#include <math.h>

#define B1 2048
#define B2 8192
#define NH 12
#define DH 64
#define DMODEL 768

typedef __attribute__((ext_vector_type(8))) short short8;
typedef __attribute__((ext_vector_type(4))) float floatx4;
typedef __attribute__((ext_vector_type(8))) unsigned short ushort8;
typedef __attribute__((ext_vector_type(4))) unsigned short ushort4v;

static __device__ __forceinline__ unsigned short f2bf(float f) {
  __bf16 b = (__bf16)f;
  return __builtin_bit_cast(unsigned short, b);
}

// async global->LDS, 16B per lane; LDS dest = wave-uniform base + lane*16
static __device__ __forceinline__ void gload16(const unsigned short* g,
                                               unsigned short* l) {
  __builtin_amdgcn_global_load_lds(
      (const __attribute__((address_space(1))) void*)g,
      (__attribute__((address_space(3))) void*)l, 16, 0, 0);
}

// ---------------------------------------------------------------------------
// f32-source bf16 MFMA GEMM tile: C[M,N] = bf16(A[M,K]) * bf16(B[N,K])^T.
// 128x128 tile, BK=32, 4 waves (2x2), 64x64/wave.
// Staging: REGISTER-PIPELINED — each lane loads its 8-float granule (2x
// float4) for step k+1 into regs during step k's MFMA, converts to bf16,
// ds_write_b128 to the same XOR-swizzled-granule LDS layout as the verified
// gload16 path. Register loads need not drain at s_barrier (the m97 stall),
// they are waited at the cvt a full MFMA-phase later.
// L2N: per-64-col L2 norm epilogue.
// ---------------------------------------------------------------------------
template <bool L2N, bool F32OUT>
static __device__ __forceinline__ void gemm_tile_f32(
    const float* __restrict__ Ag, const float* __restrict__ Bg,
    void* __restrict__ Cv, int M, int N, int K, int m0, int n0,
    unsigned short* sAh, unsigned short* sBh) {
  const int tid = threadIdx.x;
  const int wave = tid >> 6;
  const int lane = tid & 63;
  const int wm = wave >> 1;
  const int wn = wave & 1;
  const int n15 = lane & 15;
  const int quad = lane >> 4;
  const int srow = lane >> 2;
  const int cpl = (lane & 3) ^ (srow >> 2);

  floatx4 acc[4][4];
#pragma unroll
  for (int i = 0; i < 4; ++i)
#pragma unroll
    for (int j = 0; j < 4; ++j) acc[i][j] = (floatx4){0.f, 0.f, 0.f, 0.f};

  // staging registers: [jj][half]
  float4 ar[2][2], br[2][2];
  // prologue: load k-step 0
#pragma unroll
  for (int jj = 0; jj < 2; ++jj) {
    const int row = (wave * 2 + jj) * 16 + srow;
    const size_t ga = (size_t)(m0 + row) * K + cpl * 8;
    const size_t gb = (size_t)(n0 + row) * K + cpl * 8;
    ar[jj][0] = *(const float4*)&Ag[ga];
    ar[jj][1] = *(const float4*)&Ag[ga + 4];
    br[jj][0] = *(const float4*)&Bg[gb];
    br[jj][1] = *(const float4*)&Bg[gb + 4];
  }

  for (int k0 = 0; k0 < K; k0 += 32) {
    __syncthreads();  // prior step's frag reads complete
#pragma unroll
    for (int jj = 0; jj < 2; ++jj) {
      const int j = wave * 2 + jj;
      const float4 a0 = ar[jj][0], a1 = ar[jj][1];
      const float4 b0 = br[jj][0], b1 = br[jj][1];
      ushort8 ah = {f2bf(a0.x), f2bf(a0.y), f2bf(a0.z), f2bf(a0.w),
                    f2bf(a1.x), f2bf(a1.y), f2bf(a1.z), f2bf(a1.w)};
      ushort8 bh = {f2bf(b0.x), f2bf(b0.y), f2bf(b0.z), f2bf(b0.w),
                    f2bf(b1.x), f2bf(b1.y), f2bf(b1.z), f2bf(b1.w)};
      *(ushort8*)&sAh[j * 512 + lane * 8] = ah;
      *(ushort8*)&sBh[j * 512 + lane * 8] = bh;
    }
    if (k0 + 32 < K) {
#pragma unroll
      for (int jj = 0; jj < 2; ++jj) {
        const int row = (wave * 2 + jj) * 16 + srow;
        const size_t ga = (size_t)(m0 + row) * K + (k0 + 32) + cpl * 8;
        const size_t gb = (size_t)(n0 + row) * K + (k0 + 32) + cpl * 8;
        ar[jj][0] = *(const float4*)&Ag[ga];
        ar[jj][1] = *(const float4*)&Ag[ga + 4];
        br[jj][0] = *(const float4*)&Bg[gb];
        br[jj][1] = *(const float4*)&Bg[gb + 4];
      }
    }
    __syncthreads();  // publish LDS; next-step loads stay in flight

    short8 afh[4];
#pragma unroll
    for (int mt = 0; mt < 4; ++mt) {
      const int row = wm * 64 + mt * 16 + n15;
      const int off = row * 32 + ((quad ^ (n15 >> 2)) << 3);
      afh[mt] = *(const short8*)&sAh[off];
    }
#pragma unroll
    for (int nt = 0; nt < 4; ++nt) {
      const int row = wn * 64 + nt * 16 + n15;
      const int off = row * 32 + ((quad ^ (n15 >> 2)) << 3);
      const short8 bfh = *(const short8*)&sBh[off];
#pragma unroll
      for (int mt = 0; mt < 4; ++mt)
        acc[mt][nt] = __builtin_amdgcn_mfma_f32_16x16x32_bf16(afh[mt], bfh, acc[mt][nt], 0, 0, 0);
    }
  }

#pragma unroll
  for (int mt = 0; mt < 4; ++mt) {
    float scalev[4] = {1.f, 1.f, 1.f, 1.f};
    if constexpr (L2N) {
#pragma unroll
      for (int rr = 0; rr < 4; ++rr) {
        float ss = 0.f;
#pragma unroll
        for (int nt = 0; nt < 4; ++nt) ss += acc[mt][nt][rr] * acc[mt][nt][rr];
        ss += __shfl_xor(ss, 1, 64);
        ss += __shfl_xor(ss, 2, 64);
        ss += __shfl_xor(ss, 4, 64);
        ss += __shfl_xor(ss, 8, 64);
        scalev[rr] = 1.0f / fmaxf(sqrtf(ss), 1e-12f);
      }
    }
#pragma unroll
    for (int nt = 0; nt < 4; ++nt) {
#pragma unroll
      for (int rr = 0; rr < 4; ++rr) {
        const int row = m0 + wm * 64 + mt * 16 + quad * 4 + rr;
        const int col = n0 + wn * 64 + nt * 16 + n15;
        const float v = acc[mt][nt][rr] * scalev[rr];
        if constexpr (F32OUT)
          ((float*)Cv)[(size_t)row * N + col] = v;
        else
          ((unsigned short*)Cv)[(size_t)row * N + col] = f2bf(v);
      }
    }
  }
}

// ---------------------------------------------------------------------------
// Fused q-proj + k-proj + v-proj, one launch (864 blocks), f32 sources
// (prep pass eliminated — conversion fused into pipelined staging):
// [0,96) q (L2N) | [96,480) k (L2N) | [480,864) v.
// ---------------------------------------------------------------------------
__global__ __launch_bounds__(256) void qkv_proj(
    const float* __restrict__ x1, const float* __restrict__ Wq,
    const float* __restrict__ x2, const float* __restrict__ Wk,
    const float* __restrict__ Wv,
    unsigned short* __restrict__ qbf, unsigned short* __restrict__ kbf,
    unsigned short* __restrict__ vtbf) {
  __shared__ __align__(16) unsigned short sAh[4096], sBh[4096];
  const int bi = blockIdx.x;
  if (bi < 96) {
    gemm_tile_f32<true, false>(x1, Wq, qbf, B1, DMODEL, DMODEL,
                               (bi / 6) * 128, (bi % 6) * 128, sAh, sBh);
  } else if (bi < 480) {
    const int b = bi - 96;
    gemm_tile_f32<true, false>(x2, Wk, kbf, B2, DMODEL, DMODEL,
                               (b / 6) * 128, (b % 6) * 128, sAh, sBh);
  } else {
    const int b = bi - 480;
    gemm_tile_f32<false, false>(Wv, x2, vtbf, DMODEL, B2, DMODEL,
                                (b / 64) * 128, (b % 64) * 128, sAh, sBh);
  }
}

// ---------------------------------------------------------------------------
// MFMA bf16 attention — R8-verified structure (unchanged):
//  - K LDS double-buffered, ONE barrier per chunk; K prefetch 2 chunks deep.
//  - V loads hoisted to chunk start into regs, consumed by same-chunk PV.
//  - Ps wave-private LDS round trip; slab plain stores; XCD swizzle;
//    KSPLIT=2.
// ---------------------------------------------------------------------------
#define KC 128
#define KSPLIT 2
#define NCH (B2 / KSPLIT / KC)  // 32
#define PSTR 68

__global__ __launch_bounds__(256, 3) void attn_mfma(
    const unsigned short* __restrict__ qb, const unsigned short* __restrict__ kb,
    const unsigned short* __restrict__ vt, float* __restrict__ aoacc,
    float* __restrict__ lacc, const int* __restrict__ invt_p) {
  __shared__ __align__(16) unsigned short smem[25088];  // 50176 B
  // Kl dbuf: [2][128 keys][64 dims] at smem+0 / smem+8192 (shorts)
  unsigned short* Psl = smem + 16384;   // 4 waves x 32 x PSTR

  const int bid = blockIdx.x;                     // 0..767
  const int swz = (bid & 7) * 96 + (bid >> 3);    // bijective (768 % 8 == 0)
  const int zz = swz / 384;
  const int rem = swz - zz * 384;
  const int h = rem >> 5;
  const int q0 = (rem & 31) * 64;

  const float c2 = (float)invt_p[0] * 1.4426950408889634f;
  const int tid = threadIdx.x;
  const int wave = tid >> 6;
  const int lane = tid & 63;
  const int qsub = wave >> 1;
  const int ksub = wave & 1;
  const int n15 = lane & 15;
  const int quad = lane >> 4;
  const int kz0 = zz * (B2 / KSPLIT);

  unsigned short* Ps = &Psl[wave * 32 * PSTR];

  short8 qf[2][2];
#pragma unroll
  for (int qt = 0; qt < 2; ++qt)
#pragma unroll
    for (int ks = 0; ks < 2; ++ks) {
      const int qrow = q0 + qsub * 32 + qt * 16 + n15;
      qf[qt][ks] = *(const short8*)&qb[(size_t)qrow * DMODEL + h * DH + ks * 32 + quad * 8];
    }

  floatx4 oacc[2][4];
#pragma unroll
  for (int qt = 0; qt < 2; ++qt)
#pragma unroll
    for (int nt = 0; nt < 4; ++nt) oacc[qt][nt] = (floatx4){0.f, 0.f, 0.f, 0.f};
  float lsum[2] = {0.f, 0.f};

  const unsigned short* kbp = kb + (size_t)kz0 * DMODEL + h * DH;
  const unsigned short* vbp = vt + (size_t)(h * DH) * B2 + kz0;

  // prologue: load K chunk0 -> stage buf0 -> load K chunk1 -> barrier
  ushort8 kr[4];
#pragma unroll
  for (int i = 0; i < 4; ++i) {
    const int s = i * 256 + tid;
    const int key = s >> 3, cpk = s & 7, chk = cpk ^ (key & 7);
    kr[i] = *(const ushort8*)&kbp[(size_t)key * DMODEL + chk * 8];
  }
#pragma unroll
  for (int i = 0; i < 4; ++i) {
    const int s = i * 256 + tid;
    const int key = s >> 3, cpk = s & 7;
    *(ushort8*)&smem[key * 64 + cpk * 8] = kr[i];
  }
#pragma unroll
  for (int i = 0; i < 4; ++i) {
    const int s = i * 256 + tid;
    const int key = s >> 3, cpk = s & 7, chk = cpk ^ (key & 7);
    kr[i] = *(const ushort8*)&kbp[(size_t)(KC + key) * DMODEL + chk * 8];
  }
  __syncthreads();

  for (int c = 0; c < NCH; ++c) {
    unsigned short* Kb = &smem[(c & 1) * 8192];
    unsigned short* Kn = &smem[((c + 1) & 1) * 8192];
    const unsigned short* vc_ = vbp + c * KC;

    // early V issue for THIS chunk (consumed in PV below)
    ushort8 vr[8];
#pragma unroll
    for (int ks = 0; ks < 2; ++ks)
#pragma unroll
      for (int nt = 0; nt < 4; ++nt)
        vr[ks * 4 + nt] = *(const ushort8*)&vc_[
            (size_t)(nt * 16 + n15) * B2 + (ksub * 8 + ks * 4 + quad) * 8];

    // stage chunk c+1 into the other buffer; load chunk c+2
    if (c + 1 < NCH) {
#pragma unroll
      for (int i = 0; i < 4; ++i) {
        const int s = i * 256 + tid;
        const int key = s >> 3, cpk = s & 7;
        *(ushort8*)&Kn[key * 64 + cpk * 8] = kr[i];
      }
      if (c + 2 < NCH) {
        const unsigned short* k2 = kbp + (size_t)(c + 2) * KC * DMODEL;
#pragma unroll
        for (int i = 0; i < 4; ++i) {
          const int s = i * 256 + tid;
          const int key = s >> 3, cpk = s & 7, chk = cpk ^ (key & 7);
          kr[i] = *(const ushort8*)&k2[(size_t)key * DMODEL + chk * 8];
        }
      }
    }

    // ---- QK^T from Kb ----
#pragma unroll
    for (int kt = 0; kt < 4; ++kt) {
      floatx4 s0 = {0.f, 0.f, 0.f, 0.f}, s1 = {0.f, 0.f, 0.f, 0.f};
#pragma unroll
      for (int ks = 0; ks < 2; ++ks) {
        const int key = ksub * 64 + kt * 16 + n15;
        const int cp = (ks * 4 + quad) ^ (n15 & 7);
        const short8 kf = *(const short8*)&Kb[key * 64 + cp * 8];
        s0 = __builtin_amdgcn_mfma_f32_16x16x32_bf16(kf, qf[0][ks], s0, 0, 0, 0);
        s1 = __builtin_amdgcn_mfma_f32_16x16x32_bf16(kf, qf[1][ks], s1, 0, 0, 0);
      }
      ushort4v p0, p1;
#pragma unroll
      for (int r = 0; r < 4; ++r) {
        const float e0 = exp2f(fmaf(s0[r], c2, -c2));
        const float e1 = exp2f(fmaf(s1[r], c2, -c2));
        lsum[0] += e0;
        lsum[1] += e1;
        p0[r] = f2bf(e0);
        p1[r] = f2bf(e1);
      }
      *(ushort4v*)&Ps[(0 * 16 + n15) * PSTR + kt * 16 + quad * 4] = p0;
      *(ushort4v*)&Ps[(1 * 16 + n15) * PSTR + kt * 16 + quad * 4] = p1;
    }

    // ---- PV using prefetched vr ----
#pragma unroll
    for (int ks = 0; ks < 2; ++ks) {
      short8 pa[2];
#pragma unroll
      for (int qt = 0; qt < 2; ++qt)
        pa[qt] = *(const short8*)&Ps[(qt * 16 + n15) * PSTR + ks * 32 + quad * 8];
#pragma unroll
      for (int nt = 0; nt < 4; ++nt) {
        const short8 vf = __builtin_bit_cast(short8, vr[ks * 4 + nt]);
        oacc[0][nt] = __builtin_amdgcn_mfma_f32_16x16x32_bf16(pa[0], vf, oacc[0][nt], 0, 0, 0);
        oacc[1][nt] = __builtin_amdgcn_mfma_f32_16x16x32_bf16(pa[1], vf, oacc[1][nt], 0, 0, 0);
      }
    }

    __syncthreads();  // publish Kn; prior Kb readers done before next overwrite
  }

#pragma unroll
  for (int qt = 0; qt < 2; ++qt) {
    float v = lsum[qt];
    v += __shfl_xor(v, 16, 64);
    v += __shfl_xor(v, 32, 64);
    lsum[qt] = v;
  }

  float* aoz = aoacc + (size_t)zz * B1 * DMODEL;
  float* lz = lacc + (size_t)zz * B1 * NH;

  __syncthreads();
  float* Osc = (float*)smem;        // [64 q][64 d] f32 = 16384 B
  float* lsc = Osc + 4096;          // [64 q] f32 (total 16640 <= 50176)
  if (ksub == 1) {
#pragma unroll
    for (int qt = 0; qt < 2; ++qt)
#pragma unroll
      for (int nt = 0; nt < 4; ++nt)
#pragma unroll
        for (int r = 0; r < 4; ++r) {
          const int row = qsub * 32 + qt * 16 + quad * 4 + r;
          Osc[row * 64 + nt * 16 + n15] = oacc[qt][nt][r];
        }
    if (quad == 0) {
      lsc[qsub * 32 + n15] = lsum[0];
      lsc[qsub * 32 + 16 + n15] = lsum[1];
    }
  }
  __syncthreads();
  if (ksub == 0) {
#pragma unroll
    for (int qt = 0; qt < 2; ++qt)
#pragma unroll
      for (int nt = 0; nt < 4; ++nt)
#pragma unroll
        for (int r = 0; r < 4; ++r) {
          const int row = qsub * 32 + qt * 16 + quad * 4 + r;
          const float v = oacc[qt][nt][r] + Osc[row * 64 + nt * 16 + n15];
          aoz[(size_t)(q0 + row) * DMODEL + h * DH + nt * 16 + n15] = v;
        }
    if (quad == 0) {
      lz[(size_t)(q0 + qsub * 32 + n15) * NH + h] = lsum[0] + lsc[qsub * 32 + n15];
      lz[(size_t)(q0 + qsub * 32 + 16 + n15) * NH + h] =
          lsum[1] + lsc[qsub * 32 + 16 + n15];
    }
  }
}

// ---------------------------------------------------------------------------
// Wo projection with FUSED slab-sum + ao-normalize in A-staging; B staged
// from Wo f32 with inline cvt (prep eliminated).
// A[row][col] = bf16( (ao0+ao1)[row][col] / (l0+l1)[row][col>>6] ).
// C = f32 woout [B1, 768]. 96 blocks.
// ---------------------------------------------------------------------------
__global__ __launch_bounds__(256) void wo_proj(
    const float* __restrict__ aoacc, const float* __restrict__ lacc,
    const float* __restrict__ Wo, float* __restrict__ woout) {
  __shared__ __align__(16) unsigned short sAh[4096], sBh[4096];
  const int bi = blockIdx.x;
  const int m0 = (bi / 6) * 128;
  const int n0 = (bi % 6) * 128;
  const int tid = threadIdx.x;
  const int wave = tid >> 6;
  const int lane = tid & 63;
  const int wm = wave >> 1;
  const int wn = wave & 1;
  const int n15 = lane & 15;
  const int quad = lane >> 4;
  const int srow = lane >> 2;
  const int cpl = (lane & 3) ^ (srow >> 2);

  const float* ao1 = aoacc + (size_t)B1 * DMODEL;
  const float* la1 = lacc + (size_t)B1 * NH;

  floatx4 acc[4][4];
#pragma unroll
  for (int i = 0; i < 4; ++i)
#pragma unroll
    for (int j = 0; j < 4; ++j) acc[i][j] = (floatx4){0.f, 0.f, 0.f, 0.f};

  for (int k0 = 0; k0 < DMODEL; k0 += 32) {
    __syncthreads();
#pragma unroll
    for (int jj = 0; jj < 2; ++jj) {
      const int j = wave * 2 + jj;
      const int row = j * 16 + srow;
      // A: load 8 f32 from each slab, sum, normalize, convert, ds_write 16B
      const size_t ga = (size_t)(m0 + row) * DMODEL + k0 + cpl * 8;
      const float4 a0 = *(const float4*)&aoacc[ga];
      const float4 a1 = *(const float4*)&aoacc[ga + 4];
      const float4 b0 = *(const float4*)&ao1[ga];
      const float4 b1 = *(const float4*)&ao1[ga + 4];
      const int head = (k0 + cpl * 8) >> 6;
      const float lsum = lacc[(m0 + row) * NH + head] + la1[(m0 + row) * NH + head];
      const float inv = 1.0f / lsum;
      ushort8 ah = {f2bf((a0.x + b0.x) * inv), f2bf((a0.y + b0.y) * inv),
                    f2bf((a0.z + b0.z) * inv), f2bf((a0.w + b0.w) * inv),
                    f2bf((a1.x + b1.x) * inv), f2bf((a1.y + b1.y) * inv),
                    f2bf((a1.z + b1.z) * inv), f2bf((a1.w + b1.w) * inv)};
      *(ushort8*)&sAh[j * 512 + lane * 8] = ah;
      // B: load 8 f32 from Wo, convert, ds_write 16B
      const size_t gb = (size_t)(n0 + row) * DMODEL + k0 + cpl * 8;
      const float4 w0 = *(const float4*)&Wo[gb];
      const float4 w1 = *(const float4*)&Wo[gb + 4];
      ushort8 bh = {f2bf(w0.x), f2bf(w0.y), f2bf(w0.z), f2bf(w0.w),
                    f2bf(w1.x), f2bf(w1.y), f2bf(w1.z), f2bf(w1.w)};
      *(ushort8*)&sBh[j * 512 + lane * 8] = bh;
    }
    __syncthreads();

    short8 afh[4];
#pragma unroll
    for (int mt = 0; mt < 4; ++mt) {
      const int row = wm * 64 + mt * 16 + n15;
      afh[mt] = *(const short8*)&sAh[row * 32 + ((quad ^ (n15 >> 2)) << 3)];
    }
#pragma unroll
    for (int nt = 0; nt < 4; ++nt) {
      const int row = wn * 64 + nt * 16 + n15;
      const short8 bfh = *(const short8*)&sBh[row * 32 + ((quad ^ (n15 >> 2)) << 3)];
#pragma unroll
      for (int mt = 0; mt < 4; ++mt)
        acc[mt][nt] = __builtin_amdgcn_mfma_f32_16x16x32_bf16(afh[mt], bfh, acc[mt][nt], 0, 0, 0);
    }
  }

#pragma unroll
  for (int mt = 0; mt < 4; ++mt)
#pragma unroll
    for (int nt = 0; nt < 4; ++nt)
#pragma unroll
      for (int rr = 0; rr < 4; ++rr) {
        const int row = m0 + wm * 64 + mt * 16 + quad * 4 + rr;
        const int col = n0 + wn * 64 + nt * 16 + n15;
        woout[(size_t)row * DMODEL + col] = acc[mt][nt][rr];
      }
}

// ---------------------------------------------------------------------------
__global__ __launch_bounds__(256) void l2norm_rows768_out(
    const float* __restrict__ x, float* __restrict__ out) {
  const int row = blockIdx.x;
  const float* xr = &x[(size_t)row * DMODEL];
  float ss = 0.0f;
  float vals[3];
#pragma unroll
  for (int i = 0; i < 3; ++i) {
    vals[i] = xr[threadIdx.x + i * 256];
    ss += vals[i] * vals[i];
  }
#pragma unroll
  for (int off = 32; off > 0; off >>= 1) ss += __shfl_xor(ss, off, 64);
  __shared__ float ws[4];
  if ((threadIdx.x & 63) == 0) ws[threadIdx.x >> 6] = ss;
  __syncthreads();
  const float tot = ws[0] + ws[1] + ws[2] + ws[3];
  const float sc = 1.0f / fmaxf(sqrtf(tot), 1e-12f);
  float* orow = &out[(size_t)row * DMODEL];
#pragma unroll
  for (int i = 0; i < 3; ++i) orow[threadIdx.x + i * 256] = vals[i] * sc;
}

// ---------------------------------------------------------------------------
extern "C" void kernel_launch(void* const* d_in, const int* in_sizes, int n_in,
                              void* d_out, int out_size, void* d_ws,
                              size_t ws_size, hipStream_t stream) {
  const float* x1 = (const float*)d_in[0];
  const float* x2 = (const float*)d_in[1];
  const float* Wq = (const float*)d_in[2];
  const float* Wk = (const float*)d_in[3];
  const float* Wv = (const float*)d_in[4];
  const float* Wo = (const float*)d_in[5];
  const int* invt = (const int*)d_in[6];
  float* outp = (float*)d_out;

  // workspace (bytes) — alias-free now (no prep pass):
  //  aoacc 2 slabs  [0,        12582912)
  //  woout          [12582912, 18874368)
  //  vt_bf          [18874368, 31457280)
  //  lacc 2 slabs   [32636928, 32833536)
  //  q_bf           [38535168, 41680896)
  //  k_bf           [41680896, 54263808)
  char* ws = (char*)d_ws;
  float* aoacc = (float*)(ws + 0);
  float* woout = (float*)(ws + 12582912);
  unsigned short* vt_bf = (unsigned short*)(ws + 18874368);
  float* lacc = (float*)(ws + 32636928);
  unsigned short* q_bf = (unsigned short*)(ws + 38535168);
  unsigned short* k_bf = (unsigned short*)(ws + 41680896);

  // 1) q+k+v projections fused, f32 sources, pipelined reg-staging
  qkv_proj<<<864, 256, 0, stream>>>(x1, Wq, x2, Wk, Wv, q_bf, k_bf, vt_bf);
  // 2) attention (R8-verified pipeline, unchanged)
  attn_mfma<<<768, 256, 0, stream>>>(q_bf, k_bf, vt_bf, aoacc, lacc, invt);
  // 3) Wo projection with fused slab-sum + ao-normalize staging (Wo f32)
  wo_proj<<<96, 256, 0, stream>>>(aoacc, lacc, Wo, woout);
  // 4) final row l2norm
  l2norm_rows768_out<<<B1, 256, 0, stream>>>(woout, outp);
}

// Round 13
// 283.904 us; speedup vs baseline: 1.0657x; 1.0255x over previous
//
#include <hip/hip_runtime.h>
#include <hip/hip_bf16.h>
#include <math.h>

#define B1 2048
#define B2 8192
#define NH 12
#define DH 64
#define DMODEL 768

typedef __attribute__((ext_vector_type(8))) short short8;
typedef __attribute__((ext_vector_type(4))) float floatx4;
typedef __attribute__((ext_vector_type(8))) unsigned short ushort8;
typedef __attribute__((ext_vector_type(4))) unsigned short ushort4v;

static __device__ __forceinline__ unsigned short f2bf(float f) {
  __bf16 b = (__bf16)f;
  return __builtin_bit_cast(unsigned short, b);
}

// ---------------------------------------------------------------------------
// f32-source bf16 MFMA GEMM tile: C[M,N] = bf16(A[M,K]) * bf16(B[N,K])^T.
// 128x128 tile, BK=32, 4 waves (2x2), 64x64/wave.
// R13: LDS DOUBLE-BUFFERED, ONE barrier per k-step (R8-verified invariant:
// stage next-buf at iter start; the single end-of-iter barrier publishes it
// AND guarantees the parity-sharing reads of two iters ago are done).
// Staging: reg-pipelined f32 loads one k-step ahead, cvt at write.
// L2N: per-64-col L2 norm epilogue.
// ---------------------------------------------------------------------------
template <bool L2N, bool F32OUT>
static __device__ __forceinline__ void gemm_tile_f32(
    const float* __restrict__ Ag, const float* __restrict__ Bg,
    void* __restrict__ Cv, int M, int N, int K, int m0, int n0,
    unsigned short* sA, unsigned short* sB) {  // each [2][4096] shorts
  const int tid = threadIdx.x;
  const int wave = tid >> 6;
  const int lane = tid & 63;
  const int wm = wave >> 1;
  const int wn = wave & 1;
  const int n15 = lane & 15;
  const int quad = lane >> 4;
  const int srow = lane >> 2;
  const int cpl = (lane & 3) ^ (srow >> 2);
  const int nstep = K >> 5;

  floatx4 acc[4][4];
#pragma unroll
  for (int i = 0; i < 4; ++i)
#pragma unroll
    for (int j = 0; j < 4; ++j) acc[i][j] = (floatx4){0.f, 0.f, 0.f, 0.f};

  float4 ar[2][2], br[2][2];
  // load k-step 0
#pragma unroll
  for (int jj = 0; jj < 2; ++jj) {
    const int row = (wave * 2 + jj) * 16 + srow;
    const size_t ga = (size_t)(m0 + row) * K + cpl * 8;
    const size_t gb = (size_t)(n0 + row) * K + cpl * 8;
    ar[jj][0] = *(const float4*)&Ag[ga];
    ar[jj][1] = *(const float4*)&Ag[ga + 4];
    br[jj][0] = *(const float4*)&Bg[gb];
    br[jj][1] = *(const float4*)&Bg[gb + 4];
  }
  // write buf0
#pragma unroll
  for (int jj = 0; jj < 2; ++jj) {
    const int j = wave * 2 + jj;
    const float4 a0 = ar[jj][0], a1 = ar[jj][1];
    const float4 b0 = br[jj][0], b1 = br[jj][1];
    ushort8 ah = {f2bf(a0.x), f2bf(a0.y), f2bf(a0.z), f2bf(a0.w),
                  f2bf(a1.x), f2bf(a1.y), f2bf(a1.z), f2bf(a1.w)};
    ushort8 bh = {f2bf(b0.x), f2bf(b0.y), f2bf(b0.z), f2bf(b0.w),
                  f2bf(b1.x), f2bf(b1.y), f2bf(b1.z), f2bf(b1.w)};
    *(ushort8*)&sA[j * 512 + lane * 8] = ah;
    *(ushort8*)&sB[j * 512 + lane * 8] = bh;
  }
  // load k-step 1
  if (nstep > 1) {
#pragma unroll
    for (int jj = 0; jj < 2; ++jj) {
      const int row = (wave * 2 + jj) * 16 + srow;
      const size_t ga = (size_t)(m0 + row) * K + 32 + cpl * 8;
      const size_t gb = (size_t)(n0 + row) * K + 32 + cpl * 8;
      ar[jj][0] = *(const float4*)&Ag[ga];
      ar[jj][1] = *(const float4*)&Ag[ga + 4];
      br[jj][0] = *(const float4*)&Bg[gb];
      br[jj][1] = *(const float4*)&Bg[gb + 4];
    }
  }
  __syncthreads();

  for (int k = 0; k < nstep; ++k) {
    const int cb = (k & 1) * 4096;
    if (k + 1 < nstep) {
      const int nb = ((k + 1) & 1) * 4096;
#pragma unroll
      for (int jj = 0; jj < 2; ++jj) {
        const int j = wave * 2 + jj;
        const float4 a0 = ar[jj][0], a1 = ar[jj][1];
        const float4 b0 = br[jj][0], b1 = br[jj][1];
        ushort8 ah = {f2bf(a0.x), f2bf(a0.y), f2bf(a0.z), f2bf(a0.w),
                      f2bf(a1.x), f2bf(a1.y), f2bf(a1.z), f2bf(a1.w)};
        ushort8 bh = {f2bf(b0.x), f2bf(b0.y), f2bf(b0.z), f2bf(b0.w),
                      f2bf(b1.x), f2bf(b1.y), f2bf(b1.z), f2bf(b1.w)};
        *(ushort8*)&sA[nb + j * 512 + lane * 8] = ah;
        *(ushort8*)&sB[nb + j * 512 + lane * 8] = bh;
      }
      if (k + 2 < nstep) {
#pragma unroll
        for (int jj = 0; jj < 2; ++jj) {
          const int row = (wave * 2 + jj) * 16 + srow;
          const size_t ga = (size_t)(m0 + row) * K + (k + 2) * 32 + cpl * 8;
          const size_t gb = (size_t)(n0 + row) * K + (k + 2) * 32 + cpl * 8;
          ar[jj][0] = *(const float4*)&Ag[ga];
          ar[jj][1] = *(const float4*)&Ag[ga + 4];
          br[jj][0] = *(const float4*)&Bg[gb];
          br[jj][1] = *(const float4*)&Bg[gb + 4];
        }
      }
    }

    short8 afh[4];
#pragma unroll
    for (int mt = 0; mt < 4; ++mt) {
      const int row = wm * 64 + mt * 16 + n15;
      afh[mt] = *(const short8*)&sA[cb + row * 32 + ((quad ^ (n15 >> 2)) << 3)];
    }
#pragma unroll
    for (int nt = 0; nt < 4; ++nt) {
      const int row = wn * 64 + nt * 16 + n15;
      const short8 bfh = *(const short8*)&sB[cb + row * 32 + ((quad ^ (n15 >> 2)) << 3)];
#pragma unroll
      for (int mt = 0; mt < 4; ++mt)
        acc[mt][nt] = __builtin_amdgcn_mfma_f32_16x16x32_bf16(afh[mt], bfh, acc[mt][nt], 0, 0, 0);
    }
    __syncthreads();  // publish next buf; parity readers of cb are done
  }

#pragma unroll
  for (int mt = 0; mt < 4; ++mt) {
    float scalev[4] = {1.f, 1.f, 1.f, 1.f};
    if constexpr (L2N) {
#pragma unroll
      for (int rr = 0; rr < 4; ++rr) {
        float ss = 0.f;
#pragma unroll
        for (int nt = 0; nt < 4; ++nt) ss += acc[mt][nt][rr] * acc[mt][nt][rr];
        ss += __shfl_xor(ss, 1, 64);
        ss += __shfl_xor(ss, 2, 64);
        ss += __shfl_xor(ss, 4, 64);
        ss += __shfl_xor(ss, 8, 64);
        scalev[rr] = 1.0f / fmaxf(sqrtf(ss), 1e-12f);
      }
    }
#pragma unroll
    for (int nt = 0; nt < 4; ++nt) {
#pragma unroll
      for (int rr = 0; rr < 4; ++rr) {
        const int row = m0 + wm * 64 + mt * 16 + quad * 4 + rr;
        const int col = n0 + wn * 64 + nt * 16 + n15;
        const float v = acc[mt][nt][rr] * scalev[rr];
        if constexpr (F32OUT)
          ((float*)Cv)[(size_t)row * N + col] = v;
        else
          ((unsigned short*)Cv)[(size_t)row * N + col] = f2bf(v);
      }
    }
  }
}

// ---------------------------------------------------------------------------
// Fused q-proj + k-proj + v-proj, one launch (864 blocks), f32 sources:
// [0,96) q (L2N) | [96,480) k (L2N) | [480,864) v.
// ---------------------------------------------------------------------------
__global__ __launch_bounds__(256) void qkv_proj(
    const float* __restrict__ x1, const float* __restrict__ Wq,
    const float* __restrict__ x2, const float* __restrict__ Wk,
    const float* __restrict__ Wv,
    unsigned short* __restrict__ qbf, unsigned short* __restrict__ kbf,
    unsigned short* __restrict__ vtbf) {
  __shared__ __align__(16) unsigned short sA[8192], sB[8192];  // 2 bufs each
  const int bi = blockIdx.x;
  if (bi < 96) {
    gemm_tile_f32<true, false>(x1, Wq, qbf, B1, DMODEL, DMODEL,
                               (bi / 6) * 128, (bi % 6) * 128, sA, sB);
  } else if (bi < 480) {
    const int b = bi - 96;
    gemm_tile_f32<true, false>(x2, Wk, kbf, B2, DMODEL, DMODEL,
                               (b / 6) * 128, (b % 6) * 128, sA, sB);
  } else {
    const int b = bi - 480;
    gemm_tile_f32<false, false>(Wv, x2, vtbf, DMODEL, B2, DMODEL,
                                (b / 64) * 128, (b % 64) * 128, sA, sB);
  }
}

// ---------------------------------------------------------------------------
// MFMA bf16 attention — R8-verified structure (byte-identical to R12).
// ---------------------------------------------------------------------------
#define KC 128
#define KSPLIT 2
#define NCH (B2 / KSPLIT / KC)  // 32
#define PSTR 68

__global__ __launch_bounds__(256, 3) void attn_mfma(
    const unsigned short* __restrict__ qb, const unsigned short* __restrict__ kb,
    const unsigned short* __restrict__ vt, float* __restrict__ aoacc,
    float* __restrict__ lacc, const int* __restrict__ invt_p) {
  __shared__ __align__(16) unsigned short smem[25088];  // 50176 B
  unsigned short* Psl = smem + 16384;   // 4 waves x 32 x PSTR

  const int bid = blockIdx.x;                     // 0..767
  const int swz = (bid & 7) * 96 + (bid >> 3);    // bijective (768 % 8 == 0)
  const int zz = swz / 384;
  const int rem = swz - zz * 384;
  const int h = rem >> 5;
  const int q0 = (rem & 31) * 64;

  const float c2 = (float)invt_p[0] * 1.4426950408889634f;
  const int tid = threadIdx.x;
  const int wave = tid >> 6;
  const int lane = tid & 63;
  const int qsub = wave >> 1;
  const int ksub = wave & 1;
  const int n15 = lane & 15;
  const int quad = lane >> 4;
  const int kz0 = zz * (B2 / KSPLIT);

  unsigned short* Ps = &Psl[wave * 32 * PSTR];

  short8 qf[2][2];
#pragma unroll
  for (int qt = 0; qt < 2; ++qt)
#pragma unroll
    for (int ks = 0; ks < 2; ++ks) {
      const int qrow = q0 + qsub * 32 + qt * 16 + n15;
      qf[qt][ks] = *(const short8*)&qb[(size_t)qrow * DMODEL + h * DH + ks * 32 + quad * 8];
    }

  floatx4 oacc[2][4];
#pragma unroll
  for (int qt = 0; qt < 2; ++qt)
#pragma unroll
    for (int nt = 0; nt < 4; ++nt) oacc[qt][nt] = (floatx4){0.f, 0.f, 0.f, 0.f};
  float lsum[2] = {0.f, 0.f};

  const unsigned short* kbp = kb + (size_t)kz0 * DMODEL + h * DH;
  const unsigned short* vbp = vt + (size_t)(h * DH) * B2 + kz0;

  // prologue: load K chunk0 -> stage buf0 -> load K chunk1 -> barrier
  ushort8 kr[4];
#pragma unroll
  for (int i = 0; i < 4; ++i) {
    const int s = i * 256 + tid;
    const int key = s >> 3, cpk = s & 7, chk = cpk ^ (key & 7);
    kr[i] = *(const ushort8*)&kbp[(size_t)key * DMODEL + chk * 8];
  }
#pragma unroll
  for (int i = 0; i < 4; ++i) {
    const int s = i * 256 + tid;
    const int key = s >> 3, cpk = s & 7;
    *(ushort8*)&smem[key * 64 + cpk * 8] = kr[i];
  }
#pragma unroll
  for (int i = 0; i < 4; ++i) {
    const int s = i * 256 + tid;
    const int key = s >> 3, cpk = s & 7, chk = cpk ^ (key & 7);
    kr[i] = *(const ushort8*)&kbp[(size_t)(KC + key) * DMODEL + chk * 8];
  }
  __syncthreads();

  for (int c = 0; c < NCH; ++c) {
    unsigned short* Kb = &smem[(c & 1) * 8192];
    unsigned short* Kn = &smem[((c + 1) & 1) * 8192];
    const unsigned short* vc_ = vbp + c * KC;

    // early V issue for THIS chunk (consumed in PV below)
    ushort8 vr[8];
#pragma unroll
    for (int ks = 0; ks < 2; ++ks)
#pragma unroll
      for (int nt = 0; nt < 4; ++nt)
        vr[ks * 4 + nt] = *(const ushort8*)&vc_[
            (size_t)(nt * 16 + n15) * B2 + (ksub * 8 + ks * 4 + quad) * 8];

    // stage chunk c+1 into the other buffer; load chunk c+2
    if (c + 1 < NCH) {
#pragma unroll
      for (int i = 0; i < 4; ++i) {
        const int s = i * 256 + tid;
        const int key = s >> 3, cpk = s & 7;
        *(ushort8*)&Kn[key * 64 + cpk * 8] = kr[i];
      }
      if (c + 2 < NCH) {
        const unsigned short* k2 = kbp + (size_t)(c + 2) * KC * DMODEL;
#pragma unroll
        for (int i = 0; i < 4; ++i) {
          const int s = i * 256 + tid;
          const int key = s >> 3, cpk = s & 7, chk = cpk ^ (key & 7);
          kr[i] = *(const ushort8*)&k2[(size_t)key * DMODEL + chk * 8];
        }
      }
    }

    // ---- QK^T from Kb ----
#pragma unroll
    for (int kt = 0; kt < 4; ++kt) {
      floatx4 s0 = {0.f, 0.f, 0.f, 0.f}, s1 = {0.f, 0.f, 0.f, 0.f};
#pragma unroll
      for (int ks = 0; ks < 2; ++ks) {
        const int key = ksub * 64 + kt * 16 + n15;
        const int cp = (ks * 4 + quad) ^ (n15 & 7);
        const short8 kf = *(const short8*)&Kb[key * 64 + cp * 8];
        s0 = __builtin_amdgcn_mfma_f32_16x16x32_bf16(kf, qf[0][ks], s0, 0, 0, 0);
        s1 = __builtin_amdgcn_mfma_f32_16x16x32_bf16(kf, qf[1][ks], s1, 0, 0, 0);
      }
      ushort4v p0, p1;
#pragma unroll
      for (int r = 0; r < 4; ++r) {
        const float e0 = exp2f(fmaf(s0[r], c2, -c2));
        const float e1 = exp2f(fmaf(s1[r], c2, -c2));
        lsum[0] += e0;
        lsum[1] += e1;
        p0[r] = f2bf(e0);
        p1[r] = f2bf(e1);
      }
      *(ushort4v*)&Ps[(0 * 16 + n15) * PSTR + kt * 16 + quad * 4] = p0;
      *(ushort4v*)&Ps[(1 * 16 + n15) * PSTR + kt * 16 + quad * 4] = p1;
    }

    // ---- PV using prefetched vr ----
#pragma unroll
    for (int ks = 0; ks < 2; ++ks) {
      short8 pa[2];
#pragma unroll
      for (int qt = 0; qt < 2; ++qt)
        pa[qt] = *(const short8*)&Ps[(qt * 16 + n15) * PSTR + ks * 32 + quad * 8];
#pragma unroll
      for (int nt = 0; nt < 4; ++nt) {
        const short8 vf = __builtin_bit_cast(short8, vr[ks * 4 + nt]);
        oacc[0][nt] = __builtin_amdgcn_mfma_f32_16x16x32_bf16(pa[0], vf, oacc[0][nt], 0, 0, 0);
        oacc[1][nt] = __builtin_amdgcn_mfma_f32_16x16x32_bf16(pa[1], vf, oacc[1][nt], 0, 0, 0);
      }
    }

    __syncthreads();  // publish Kn; prior Kb readers done before next overwrite
  }

#pragma unroll
  for (int qt = 0; qt < 2; ++qt) {
    float v = lsum[qt];
    v += __shfl_xor(v, 16, 64);
    v += __shfl_xor(v, 32, 64);
    lsum[qt] = v;
  }

  float* aoz = aoacc + (size_t)zz * B1 * DMODEL;
  float* lz = lacc + (size_t)zz * B1 * NH;

  __syncthreads();
  float* Osc = (float*)smem;        // [64 q][64 d] f32 = 16384 B
  float* lsc = Osc + 4096;          // [64 q] f32 (total 16640 <= 50176)
  if (ksub == 1) {
#pragma unroll
    for (int qt = 0; qt < 2; ++qt)
#pragma unroll
      for (int nt = 0; nt < 4; ++nt)
#pragma unroll
        for (int r = 0; r < 4; ++r) {
          const int row = qsub * 32 + qt * 16 + quad * 4 + r;
          Osc[row * 64 + nt * 16 + n15] = oacc[qt][nt][r];
        }
    if (quad == 0) {
      lsc[qsub * 32 + n15] = lsum[0];
      lsc[qsub * 32 + 16 + n15] = lsum[1];
    }
  }
  __syncthreads();
  if (ksub == 0) {
#pragma unroll
    for (int qt = 0; qt < 2; ++qt)
#pragma unroll
      for (int nt = 0; nt < 4; ++nt)
#pragma unroll
        for (int r = 0; r < 4; ++r) {
          const int row = qsub * 32 + qt * 16 + quad * 4 + r;
          const float v = oacc[qt][nt][r] + Osc[row * 64 + nt * 16 + n15];
          aoz[(size_t)(q0 + row) * DMODEL + h * DH + nt * 16 + n15] = v;
        }
    if (quad == 0) {
      lz[(size_t)(q0 + qsub * 32 + n15) * NH + h] = lsum[0] + lsc[qsub * 32 + n15];
      lz[(size_t)(q0 + qsub * 32 + 16 + n15) * NH + h] =
          lsum[1] + lsc[qsub * 32 + 16 + n15];
    }
  }
}

// ---------------------------------------------------------------------------
// Wo projection, SPLIT-K x3 (grid 288 = 96 tiles x 3 k-slabs of 256) with
// single-barrier double-buffered staging. A = (ao0+ao1)/lsum cvt bf16,
// B = bf16(Wo). Output: woout slab kz (f32), summed in l2norm.
// ---------------------------------------------------------------------------
__global__ __launch_bounds__(256) void wo_proj(
    const float* __restrict__ aoacc, const float* __restrict__ lacc,
    const float* __restrict__ Wo, float* __restrict__ woout) {
  __shared__ __align__(16) unsigned short sA[8192], sB[8192];
  const int bid = blockIdx.x;
  const int t = bid % 96;
  const int kz = bid / 96;
  const int m0 = (t / 6) * 128;
  const int n0 = (t % 6) * 128;
  const int kbase = kz * 256;
  const int nstep = 8;  // 256 / 32
  const int tid = threadIdx.x;
  const int wave = tid >> 6;
  const int lane = tid & 63;
  const int wm = wave >> 1;
  const int wn = wave & 1;
  const int n15 = lane & 15;
  const int quad = lane >> 4;
  const int srow = lane >> 2;
  const int cpl = (lane & 3) ^ (srow >> 2);

  const float* ao1 = aoacc + (size_t)B1 * DMODEL;
  const float* la1 = lacc + (size_t)B1 * NH;

  floatx4 acc[4][4];
#pragma unroll
  for (int i = 0; i < 4; ++i)
#pragma unroll
    for (int j = 0; j < 4; ++j) acc[i][j] = (floatx4){0.f, 0.f, 0.f, 0.f};

  float4 Aa[2][2], Ab[2][2], Bw[2][2];
  float lw[2];

  // loadstep(s) into regs
#define WO_LOADSTEP(s)                                                        \
  {                                                                           \
    const int kk = kbase + (s) * 32;                                          \
    _Pragma("unroll") for (int jj = 0; jj < 2; ++jj) {                        \
      const int row = (wave * 2 + jj) * 16 + srow;                            \
      const size_t ga = (size_t)(m0 + row) * DMODEL + kk + cpl * 8;           \
      const size_t gb = (size_t)(n0 + row) * DMODEL + kk + cpl * 8;           \
      Aa[jj][0] = *(const float4*)&aoacc[ga];                                 \
      Aa[jj][1] = *(const float4*)&aoacc[ga + 4];                             \
      Ab[jj][0] = *(const float4*)&ao1[ga];                                   \
      Ab[jj][1] = *(const float4*)&ao1[ga + 4];                               \
      Bw[jj][0] = *(const float4*)&Wo[gb];                                    \
      Bw[jj][1] = *(const float4*)&Wo[gb + 4];                                \
      const int head = (kk + cpl * 8) >> 6;                                   \
      const int li = (m0 + row) * NH + head;                                  \
      lw[jj] = lacc[li] + la1[li];                                            \
    }                                                                         \
  }

#define WO_WRITEBUF(boff)                                                     \
  {                                                                           \
    _Pragma("unroll") for (int jj = 0; jj < 2; ++jj) {                        \
      const int j = wave * 2 + jj;                                            \
      const float inv = 1.0f / lw[jj];                                        \
      const float4 a0 = Aa[jj][0], a1 = Aa[jj][1];                            \
      const float4 b0 = Ab[jj][0], b1 = Ab[jj][1];                            \
      const float4 w0 = Bw[jj][0], w1 = Bw[jj][1];                            \
      ushort8 ah = {f2bf((a0.x + b0.x) * inv), f2bf((a0.y + b0.y) * inv),     \
                    f2bf((a0.z + b0.z) * inv), f2bf((a0.w + b0.w) * inv),     \
                    f2bf((a1.x + b1.x) * inv), f2bf((a1.y + b1.y) * inv),     \
                    f2bf((a1.z + b1.z) * inv), f2bf((a1.w + b1.w) * inv)};    \
      ushort8 bh = {f2bf(w0.x), f2bf(w0.y), f2bf(w0.z), f2bf(w0.w),           \
                    f2bf(w1.x), f2bf(w1.y), f2bf(w1.z), f2bf(w1.w)};          \
      *(ushort8*)&sA[(boff) + j * 512 + lane * 8] = ah;                       \
      *(ushort8*)&sB[(boff) + j * 512 + lane * 8] = bh;                       \
    }                                                                         \
  }

  WO_LOADSTEP(0);
  WO_WRITEBUF(0);
  WO_LOADSTEP(1);
  __syncthreads();

  for (int k = 0; k < nstep; ++k) {
    const int cb = (k & 1) * 4096;
    if (k + 1 < nstep) {
      const int nb = ((k + 1) & 1) * 4096;
      WO_WRITEBUF(nb);
      if (k + 2 < nstep) WO_LOADSTEP(k + 2);
    }

    short8 afh[4];
#pragma unroll
    for (int mt = 0; mt < 4; ++mt) {
      const int row = wm * 64 + mt * 16 + n15;
      afh[mt] = *(const short8*)&sA[cb + row * 32 + ((quad ^ (n15 >> 2)) << 3)];
    }
#pragma unroll
    for (int nt = 0; nt < 4; ++nt) {
      const int row = wn * 64 + nt * 16 + n15;
      const short8 bfh = *(const short8*)&sB[cb + row * 32 + ((quad ^ (n15 >> 2)) << 3)];
#pragma unroll
      for (int mt = 0; mt < 4; ++mt)
        acc[mt][nt] = __builtin_amdgcn_mfma_f32_16x16x32_bf16(afh[mt], bfh, acc[mt][nt], 0, 0, 0);
    }
    __syncthreads();
  }

  float* wslab = woout + (size_t)kz * B1 * DMODEL;
#pragma unroll
  for (int mt = 0; mt < 4; ++mt)
#pragma unroll
    for (int nt = 0; nt < 4; ++nt)
#pragma unroll
      for (int rr = 0; rr < 4; ++rr) {
        const int row = m0 + wm * 64 + mt * 16 + quad * 4 + rr;
        const int col = n0 + wn * 64 + nt * 16 + n15;
        wslab[(size_t)row * DMODEL + col] = acc[mt][nt][rr];
      }
#undef WO_LOADSTEP
#undef WO_WRITEBUF
}

// ---------------------------------------------------------------------------
// Final row l2norm, summing the 3 wo split-K slabs.
// ---------------------------------------------------------------------------
__global__ __launch_bounds__(256) void l2norm_rows768_out(
    const float* __restrict__ x, float* __restrict__ out) {
  const int row = blockIdx.x;
  const float* x0 = &x[(size_t)row * DMODEL];
  const float* x1s = x0 + (size_t)B1 * DMODEL;
  const float* x2s = x0 + 2 * (size_t)B1 * DMODEL;
  float ss = 0.0f;
  float vals[3];
#pragma unroll
  for (int i = 0; i < 3; ++i) {
    const int c = threadIdx.x + i * 256;
    vals[i] = x0[c] + x1s[c] + x2s[c];
    ss += vals[i] * vals[i];
  }
#pragma unroll
  for (int off = 32; off > 0; off >>= 1) ss += __shfl_xor(ss, off, 64);
  __shared__ float ws[4];
  if ((threadIdx.x & 63) == 0) ws[threadIdx.x >> 6] = ss;
  __syncthreads();
  const float tot = ws[0] + ws[1] + ws[2] + ws[3];
  const float sc = 1.0f / fmaxf(sqrtf(tot), 1e-12f);
  float* orow = &out[(size_t)row * DMODEL];
#pragma unroll
  for (int i = 0; i < 3; ++i) orow[threadIdx.x + i * 256] = vals[i] * sc;
}

// ---------------------------------------------------------------------------
extern "C" void kernel_launch(void* const* d_in, const int* in_sizes, int n_in,
                              void* d_out, int out_size, void* d_ws,
                              size_t ws_size, hipStream_t stream) {
  const float* x1 = (const float*)d_in[0];
  const float* x2 = (const float*)d_in[1];
  const float* Wq = (const float*)d_in[2];
  const float* Wk = (const float*)d_in[3];
  const float* Wv = (const float*)d_in[4];
  const float* Wo = (const float*)d_in[5];
  const int* invt = (const int*)d_in[6];
  float* outp = (float*)d_out;

  // workspace (bytes):
  //  aoacc 2 slabs   [0,        12582912)
  //  woout 3 slabs   [12582912, 31457280)  (slab1/2 overlay vt region,
  //                                         which is dead after attn)
  //  vt_bf           [18874368, 31457280)
  //  lacc 2 slabs    [32636928, 32833536)
  //  q_bf            [38535168, 41680896)
  //  k_bf            [41680896, 54263808)
  char* ws = (char*)d_ws;
  float* aoacc = (float*)(ws + 0);
  float* woout = (float*)(ws + 12582912);
  unsigned short* vt_bf = (unsigned short*)(ws + 18874368);
  float* lacc = (float*)(ws + 32636928);
  unsigned short* q_bf = (unsigned short*)(ws + 38535168);
  unsigned short* k_bf = (unsigned short*)(ws + 41680896);

  // 1) q+k+v projections fused, f32 sources, single-barrier dbuf staging
  qkv_proj<<<864, 256, 0, stream>>>(x1, Wq, x2, Wk, Wv, q_bf, k_bf, vt_bf);
  // 2) attention (R8-verified pipeline, unchanged)
  attn_mfma<<<768, 256, 0, stream>>>(q_bf, k_bf, vt_bf, aoacc, lacc, invt);
  // 3) Wo projection, split-K x3, dbuf staging (slab1/2 overwrite dead vt)
  wo_proj<<<288, 256, 0, stream>>>(aoacc, lacc, Wo, woout);
  // 4) final row l2norm over 3 slabs
  l2norm_rows768_out<<<B1, 256, 0, stream>>>(woout, outp);
}

// Round 14
// 271.276 us; speedup vs baseline: 1.1153x; 1.0466x over previous
//
#include <hip/hip_runtime.h>
#include <hip/hip_bf16.h>
#include <math.h>

#define B1 2048
#define B2 8192
#define NH 12
#define DH 64
#define DMODEL 768

typedef __attribute__((ext_vector_type(8))) short short8;
typedef __attribute__((ext_vector_type(4))) float floatx4;
typedef __attribute__((ext_vector_type(8))) unsigned short ushort8;
typedef __attribute__((ext_vector_type(4))) unsigned short ushort4v;

static __device__ __forceinline__ unsigned short f2bf(float f) {
  __bf16 b = (__bf16)f;
  return __builtin_bit_cast(unsigned short, b);
}

// ---------------------------------------------------------------------------
// f32-source bf16 MFMA GEMM tile: C[M,N] = bf16(A[M,K]) * bf16(B[N,K])^T.
// 128x128 tile, BK=32, 4 waves (2x2), 64x64/wave.
// LDS double-buffered, ONE barrier per k-step (R8/R13-verified invariant).
// Staging: reg-pipelined f32 loads one k-step ahead, cvt at write.
// L2N: per-64-col L2 norm epilogue.
// ---------------------------------------------------------------------------
template <bool L2N, bool F32OUT>
static __device__ __forceinline__ void gemm_tile_f32(
    const float* __restrict__ Ag, const float* __restrict__ Bg,
    void* __restrict__ Cv, int M, int N, int K, int m0, int n0,
    unsigned short* sA, unsigned short* sB) {  // each [2][4096] shorts
  const int tid = threadIdx.x;
  const int wave = tid >> 6;
  const int lane = tid & 63;
  const int wm = wave >> 1;
  const int wn = wave & 1;
  const int n15 = lane & 15;
  const int quad = lane >> 4;
  const int srow = lane >> 2;
  const int cpl = (lane & 3) ^ (srow >> 2);
  const int nstep = K >> 5;

  floatx4 acc[4][4];
#pragma unroll
  for (int i = 0; i < 4; ++i)
#pragma unroll
    for (int j = 0; j < 4; ++j) acc[i][j] = (floatx4){0.f, 0.f, 0.f, 0.f};

  float4 ar[2][2], br[2][2];
  // load k-step 0
#pragma unroll
  for (int jj = 0; jj < 2; ++jj) {
    const int row = (wave * 2 + jj) * 16 + srow;
    const size_t ga = (size_t)(m0 + row) * K + cpl * 8;
    const size_t gb = (size_t)(n0 + row) * K + cpl * 8;
    ar[jj][0] = *(const float4*)&Ag[ga];
    ar[jj][1] = *(const float4*)&Ag[ga + 4];
    br[jj][0] = *(const float4*)&Bg[gb];
    br[jj][1] = *(const float4*)&Bg[gb + 4];
  }
  // write buf0
#pragma unroll
  for (int jj = 0; jj < 2; ++jj) {
    const int j = wave * 2 + jj;
    const float4 a0 = ar[jj][0], a1 = ar[jj][1];
    const float4 b0 = br[jj][0], b1 = br[jj][1];
    ushort8 ah = {f2bf(a0.x), f2bf(a0.y), f2bf(a0.z), f2bf(a0.w),
                  f2bf(a1.x), f2bf(a1.y), f2bf(a1.z), f2bf(a1.w)};
    ushort8 bh = {f2bf(b0.x), f2bf(b0.y), f2bf(b0.z), f2bf(b0.w),
                  f2bf(b1.x), f2bf(b1.y), f2bf(b1.z), f2bf(b1.w)};
    *(ushort8*)&sA[j * 512 + lane * 8] = ah;
    *(ushort8*)&sB[j * 512 + lane * 8] = bh;
  }
  // load k-step 1
  if (nstep > 1) {
#pragma unroll
    for (int jj = 0; jj < 2; ++jj) {
      const int row = (wave * 2 + jj) * 16 + srow;
      const size_t ga = (size_t)(m0 + row) * K + 32 + cpl * 8;
      const size_t gb = (size_t)(n0 + row) * K + 32 + cpl * 8;
      ar[jj][0] = *(const float4*)&Ag[ga];
      ar[jj][1] = *(const float4*)&Ag[ga + 4];
      br[jj][0] = *(const float4*)&Bg[gb];
      br[jj][1] = *(const float4*)&Bg[gb + 4];
    }
  }
  __syncthreads();

  for (int k = 0; k < nstep; ++k) {
    const int cb = (k & 1) * 4096;
    if (k + 1 < nstep) {
      const int nb = ((k + 1) & 1) * 4096;
#pragma unroll
      for (int jj = 0; jj < 2; ++jj) {
        const int j = wave * 2 + jj;
        const float4 a0 = ar[jj][0], a1 = ar[jj][1];
        const float4 b0 = br[jj][0], b1 = br[jj][1];
        ushort8 ah = {f2bf(a0.x), f2bf(a0.y), f2bf(a0.z), f2bf(a0.w),
                      f2bf(a1.x), f2bf(a1.y), f2bf(a1.z), f2bf(a1.w)};
        ushort8 bh = {f2bf(b0.x), f2bf(b0.y), f2bf(b0.z), f2bf(b0.w),
                      f2bf(b1.x), f2bf(b1.y), f2bf(b1.z), f2bf(b1.w)};
        *(ushort8*)&sA[nb + j * 512 + lane * 8] = ah;
        *(ushort8*)&sB[nb + j * 512 + lane * 8] = bh;
      }
      if (k + 2 < nstep) {
#pragma unroll
        for (int jj = 0; jj < 2; ++jj) {
          const int row = (wave * 2 + jj) * 16 + srow;
          const size_t ga = (size_t)(m0 + row) * K + (k + 2) * 32 + cpl * 8;
          const size_t gb = (size_t)(n0 + row) * K + (k + 2) * 32 + cpl * 8;
          ar[jj][0] = *(const float4*)&Ag[ga];
          ar[jj][1] = *(const float4*)&Ag[ga + 4];
          br[jj][0] = *(const float4*)&Bg[gb];
          br[jj][1] = *(const float4*)&Bg[gb + 4];
        }
      }
    }

    short8 afh[4];
#pragma unroll
    for (int mt = 0; mt < 4; ++mt) {
      const int row = wm * 64 + mt * 16 + n15;
      afh[mt] = *(const short8*)&sA[cb + row * 32 + ((quad ^ (n15 >> 2)) << 3)];
    }
#pragma unroll
    for (int nt = 0; nt < 4; ++nt) {
      const int row = wn * 64 + nt * 16 + n15;
      const short8 bfh = *(const short8*)&sB[cb + row * 32 + ((quad ^ (n15 >> 2)) << 3)];
#pragma unroll
      for (int mt = 0; mt < 4; ++mt)
        acc[mt][nt] = __builtin_amdgcn_mfma_f32_16x16x32_bf16(afh[mt], bfh, acc[mt][nt], 0, 0, 0);
    }
    __syncthreads();  // publish next buf; parity readers of cb are done
  }

#pragma unroll
  for (int mt = 0; mt < 4; ++mt) {
    float scalev[4] = {1.f, 1.f, 1.f, 1.f};
    if constexpr (L2N) {
#pragma unroll
      for (int rr = 0; rr < 4; ++rr) {
        float ss = 0.f;
#pragma unroll
        for (int nt = 0; nt < 4; ++nt) ss += acc[mt][nt][rr] * acc[mt][nt][rr];
        ss += __shfl_xor(ss, 1, 64);
        ss += __shfl_xor(ss, 2, 64);
        ss += __shfl_xor(ss, 4, 64);
        ss += __shfl_xor(ss, 8, 64);
        scalev[rr] = 1.0f / fmaxf(sqrtf(ss), 1e-12f);
      }
    }
#pragma unroll
    for (int nt = 0; nt < 4; ++nt) {
#pragma unroll
      for (int rr = 0; rr < 4; ++rr) {
        const int row = m0 + wm * 64 + mt * 16 + quad * 4 + rr;
        const int col = n0 + wn * 64 + nt * 16 + n15;
        const float v = acc[mt][nt][rr] * scalev[rr];
        if constexpr (F32OUT)
          ((float*)Cv)[(size_t)row * N + col] = v;
        else
          ((unsigned short*)Cv)[(size_t)row * N + col] = f2bf(v);
      }
    }
  }
}

// ---------------------------------------------------------------------------
// Fused q+k+v projections, one launch (864 blocks), f32 sources.
// SEGMENT-LOCAL XCD swizzle (fix of R10's whole-launch failure): permute
// within each GEMM's range only — every XCD gets a type-balanced slice
// (12 q + 48 k + 48 v) with panel-contiguous logical ids, so blocks sharing
// an A-panel co-reside on one L2 (R6-measured mechanism). All segment
// lengths are multiples of 8 and start at bid % 8 == 0, so xcd = bid%8
// composes bijectively with each local permutation.
// [0,96) q (L2N) | [96,480) k (L2N) | [480,864) v.
// ---------------------------------------------------------------------------
__global__ __launch_bounds__(256) void qkv_proj(
    const float* __restrict__ x1, const float* __restrict__ Wq,
    const float* __restrict__ x2, const float* __restrict__ Wk,
    const float* __restrict__ Wv,
    unsigned short* __restrict__ qbf, unsigned short* __restrict__ kbf,
    unsigned short* __restrict__ vtbf) {
  __shared__ __align__(16) unsigned short sA[8192], sB[8192];  // 2 bufs each
  const int bid = blockIdx.x;
  if (bid < 96) {
    const int b = (bid & 7) * 12 + (bid >> 3);            // 96 = 8*12
    gemm_tile_f32<true, false>(x1, Wq, qbf, B1, DMODEL, DMODEL,
                               (b / 6) * 128, (b % 6) * 128, sA, sB);
  } else if (bid < 480) {
    const int lb = bid - 96;
    const int b = (lb & 7) * 48 + (lb >> 3);              // 384 = 8*48
    gemm_tile_f32<true, false>(x2, Wk, kbf, B2, DMODEL, DMODEL,
                               (b / 6) * 128, (b % 6) * 128, sA, sB);
  } else {
    const int lb = bid - 480;
    const int b = (lb & 7) * 48 + (lb >> 3);              // 384 = 8*48
    gemm_tile_f32<false, false>(Wv, x2, vtbf, DMODEL, B2, DMODEL,
                                (b / 64) * 128, (b % 64) * 128, sA, sB);
  }
}

// ---------------------------------------------------------------------------
// MFMA bf16 attention — R8-verified structure (byte-identical to R13).
// ---------------------------------------------------------------------------
#define KC 128
#define KSPLIT 2
#define NCH (B2 / KSPLIT / KC)  // 32
#define PSTR 68

__global__ __launch_bounds__(256, 3) void attn_mfma(
    const unsigned short* __restrict__ qb, const unsigned short* __restrict__ kb,
    const unsigned short* __restrict__ vt, float* __restrict__ aoacc,
    float* __restrict__ lacc, const int* __restrict__ invt_p) {
  __shared__ __align__(16) unsigned short smem[25088];  // 50176 B
  unsigned short* Psl = smem + 16384;   // 4 waves x 32 x PSTR

  const int bid = blockIdx.x;                     // 0..767
  const int swz = (bid & 7) * 96 + (bid >> 3);    // bijective (768 % 8 == 0)
  const int zz = swz / 384;
  const int rem = swz - zz * 384;
  const int h = rem >> 5;
  const int q0 = (rem & 31) * 64;

  const float c2 = (float)invt_p[0] * 1.4426950408889634f;
  const int tid = threadIdx.x;
  const int wave = tid >> 6;
  const int lane = tid & 63;
  const int qsub = wave >> 1;
  const int ksub = wave & 1;
  const int n15 = lane & 15;
  const int quad = lane >> 4;
  const int kz0 = zz * (B2 / KSPLIT);

  unsigned short* Ps = &Psl[wave * 32 * PSTR];

  short8 qf[2][2];
#pragma unroll
  for (int qt = 0; qt < 2; ++qt)
#pragma unroll
    for (int ks = 0; ks < 2; ++ks) {
      const int qrow = q0 + qsub * 32 + qt * 16 + n15;
      qf[qt][ks] = *(const short8*)&qb[(size_t)qrow * DMODEL + h * DH + ks * 32 + quad * 8];
    }

  floatx4 oacc[2][4];
#pragma unroll
  for (int qt = 0; qt < 2; ++qt)
#pragma unroll
    for (int nt = 0; nt < 4; ++nt) oacc[qt][nt] = (floatx4){0.f, 0.f, 0.f, 0.f};
  float lsum[2] = {0.f, 0.f};

  const unsigned short* kbp = kb + (size_t)kz0 * DMODEL + h * DH;
  const unsigned short* vbp = vt + (size_t)(h * DH) * B2 + kz0;

  // prologue: load K chunk0 -> stage buf0 -> load K chunk1 -> barrier
  ushort8 kr[4];
#pragma unroll
  for (int i = 0; i < 4; ++i) {
    const int s = i * 256 + tid;
    const int key = s >> 3, cpk = s & 7, chk = cpk ^ (key & 7);
    kr[i] = *(const ushort8*)&kbp[(size_t)key * DMODEL + chk * 8];
  }
#pragma unroll
  for (int i = 0; i < 4; ++i) {
    const int s = i * 256 + tid;
    const int key = s >> 3, cpk = s & 7;
    *(ushort8*)&smem[key * 64 + cpk * 8] = kr[i];
  }
#pragma unroll
  for (int i = 0; i < 4; ++i) {
    const int s = i * 256 + tid;
    const int key = s >> 3, cpk = s & 7, chk = cpk ^ (key & 7);
    kr[i] = *(const ushort8*)&kbp[(size_t)(KC + key) * DMODEL + chk * 8];
  }
  __syncthreads();

  for (int c = 0; c < NCH; ++c) {
    unsigned short* Kb = &smem[(c & 1) * 8192];
    unsigned short* Kn = &smem[((c + 1) & 1) * 8192];
    const unsigned short* vc_ = vbp + c * KC;

    // early V issue for THIS chunk (consumed in PV below)
    ushort8 vr[8];
#pragma unroll
    for (int ks = 0; ks < 2; ++ks)
#pragma unroll
      for (int nt = 0; nt < 4; ++nt)
        vr[ks * 4 + nt] = *(const ushort8*)&vc_[
            (size_t)(nt * 16 + n15) * B2 + (ksub * 8 + ks * 4 + quad) * 8];

    // stage chunk c+1 into the other buffer; load chunk c+2
    if (c + 1 < NCH) {
#pragma unroll
      for (int i = 0; i < 4; ++i) {
        const int s = i * 256 + tid;
        const int key = s >> 3, cpk = s & 7;
        *(ushort8*)&Kn[key * 64 + cpk * 8] = kr[i];
      }
      if (c + 2 < NCH) {
        const unsigned short* k2 = kbp + (size_t)(c + 2) * KC * DMODEL;
#pragma unroll
        for (int i = 0; i < 4; ++i) {
          const int s = i * 256 + tid;
          const int key = s >> 3, cpk = s & 7, chk = cpk ^ (key & 7);
          kr[i] = *(const ushort8*)&k2[(size_t)key * DMODEL + chk * 8];
        }
      }
    }

    // ---- QK^T from Kb ----
#pragma unroll
    for (int kt = 0; kt < 4; ++kt) {
      floatx4 s0 = {0.f, 0.f, 0.f, 0.f}, s1 = {0.f, 0.f, 0.f, 0.f};
#pragma unroll
      for (int ks = 0; ks < 2; ++ks) {
        const int key = ksub * 64 + kt * 16 + n15;
        const int cp = (ks * 4 + quad) ^ (n15 & 7);
        const short8 kf = *(const short8*)&Kb[key * 64 + cp * 8];
        s0 = __builtin_amdgcn_mfma_f32_16x16x32_bf16(kf, qf[0][ks], s0, 0, 0, 0);
        s1 = __builtin_amdgcn_mfma_f32_16x16x32_bf16(kf, qf[1][ks], s1, 0, 0, 0);
      }
      ushort4v p0, p1;
#pragma unroll
      for (int r = 0; r < 4; ++r) {
        const float e0 = exp2f(fmaf(s0[r], c2, -c2));
        const float e1 = exp2f(fmaf(s1[r], c2, -c2));
        lsum[0] += e0;
        lsum[1] += e1;
        p0[r] = f2bf(e0);
        p1[r] = f2bf(e1);
      }
      *(ushort4v*)&Ps[(0 * 16 + n15) * PSTR + kt * 16 + quad * 4] = p0;
      *(ushort4v*)&Ps[(1 * 16 + n15) * PSTR + kt * 16 + quad * 4] = p1;
    }

    // ---- PV using prefetched vr ----
#pragma unroll
    for (int ks = 0; ks < 2; ++ks) {
      short8 pa[2];
#pragma unroll
      for (int qt = 0; qt < 2; ++qt)
        pa[qt] = *(const short8*)&Ps[(qt * 16 + n15) * PSTR + ks * 32 + quad * 8];
#pragma unroll
      for (int nt = 0; nt < 4; ++nt) {
        const short8 vf = __builtin_bit_cast(short8, vr[ks * 4 + nt]);
        oacc[0][nt] = __builtin_amdgcn_mfma_f32_16x16x32_bf16(pa[0], vf, oacc[0][nt], 0, 0, 0);
        oacc[1][nt] = __builtin_amdgcn_mfma_f32_16x16x32_bf16(pa[1], vf, oacc[1][nt], 0, 0, 0);
      }
    }

    __syncthreads();  // publish Kn; prior Kb readers done before next overwrite
  }

#pragma unroll
  for (int qt = 0; qt < 2; ++qt) {
    float v = lsum[qt];
    v += __shfl_xor(v, 16, 64);
    v += __shfl_xor(v, 32, 64);
    lsum[qt] = v;
  }

  float* aoz = aoacc + (size_t)zz * B1 * DMODEL;
  float* lz = lacc + (size_t)zz * B1 * NH;

  __syncthreads();
  float* Osc = (float*)smem;        // [64 q][64 d] f32 = 16384 B
  float* lsc = Osc + 4096;          // [64 q] f32 (total 16640 <= 50176)
  if (ksub == 1) {
#pragma unroll
    for (int qt = 0; qt < 2; ++qt)
#pragma unroll
      for (int nt = 0; nt < 4; ++nt)
#pragma unroll
        for (int r = 0; r < 4; ++r) {
          const int row = qsub * 32 + qt * 16 + quad * 4 + r;
          Osc[row * 64 + nt * 16 + n15] = oacc[qt][nt][r];
        }
    if (quad == 0) {
      lsc[qsub * 32 + n15] = lsum[0];
      lsc[qsub * 32 + 16 + n15] = lsum[1];
    }
  }
  __syncthreads();
  if (ksub == 0) {
#pragma unroll
    for (int qt = 0; qt < 2; ++qt)
#pragma unroll
      for (int nt = 0; nt < 4; ++nt)
#pragma unroll
        for (int r = 0; r < 4; ++r) {
          const int row = qsub * 32 + qt * 16 + quad * 4 + r;
          const float v = oacc[qt][nt][r] + Osc[row * 64 + nt * 16 + n15];
          aoz[(size_t)(q0 + row) * DMODEL + h * DH + nt * 16 + n15] = v;
        }
    if (quad == 0) {
      lz[(size_t)(q0 + qsub * 32 + n15) * NH + h] = lsum[0] + lsc[qsub * 32 + n15];
      lz[(size_t)(q0 + qsub * 32 + 16 + n15) * NH + h] =
          lsum[1] + lsc[qsub * 32 + 16 + n15];
    }
  }
}

// ---------------------------------------------------------------------------
// Wo projection, SPLIT-K x3 (grid 288 = 3 kz slabs x 96 tiles) with
// single-barrier double-buffered staging and per-kz-segment XCD swizzle
// (96 = 8*12, segment bases 0/96/192 all ≡ 0 mod 8).
// A = (ao0+ao1)/lsum cvt bf16, B = bf16(Wo). Output slab kz, summed in l2norm.
// ---------------------------------------------------------------------------
__global__ __launch_bounds__(256) void wo_proj(
    const float* __restrict__ aoacc, const float* __restrict__ lacc,
    const float* __restrict__ Wo, float* __restrict__ woout) {
  __shared__ __align__(16) unsigned short sA[8192], sB[8192];
  const int bid = blockIdx.x;
  const int kz = bid / 96;
  const int lb = bid % 96;
  const int t = (lb & 7) * 12 + (lb >> 3);   // segment-local XCD swizzle
  const int m0 = (t / 6) * 128;
  const int n0 = (t % 6) * 128;
  const int kbase = kz * 256;
  const int nstep = 8;  // 256 / 32
  const int tid = threadIdx.x;
  const int wave = tid >> 6;
  const int lane = tid & 63;
  const int wm = wave >> 1;
  const int wn = wave & 1;
  const int n15 = lane & 15;
  const int quad = lane >> 4;
  const int srow = lane >> 2;
  const int cpl = (lane & 3) ^ (srow >> 2);

  const float* ao1 = aoacc + (size_t)B1 * DMODEL;
  const float* la1 = lacc + (size_t)B1 * NH;

  floatx4 acc[4][4];
#pragma unroll
  for (int i = 0; i < 4; ++i)
#pragma unroll
    for (int j = 0; j < 4; ++j) acc[i][j] = (floatx4){0.f, 0.f, 0.f, 0.f};

  float4 Aa[2][2], Ab[2][2], Bw[2][2];
  float lw[2];

#define WO_LOADSTEP(s)                                                        \
  {                                                                           \
    const int kk = kbase + (s) * 32;                                          \
    _Pragma("unroll") for (int jj = 0; jj < 2; ++jj) {                        \
      const int row = (wave * 2 + jj) * 16 + srow;                            \
      const size_t ga = (size_t)(m0 + row) * DMODEL + kk + cpl * 8;           \
      const size_t gb = (size_t)(n0 + row) * DMODEL + kk + cpl * 8;           \
      Aa[jj][0] = *(const float4*)&aoacc[ga];                                 \
      Aa[jj][1] = *(const float4*)&aoacc[ga + 4];                             \
      Ab[jj][0] = *(const float4*)&ao1[ga];                                   \
      Ab[jj][1] = *(const float4*)&ao1[ga + 4];                               \
      Bw[jj][0] = *(const float4*)&Wo[gb];                                    \
      Bw[jj][1] = *(const float4*)&Wo[gb + 4];                                \
      const int head = (kk + cpl * 8) >> 6;                                   \
      const int li = (m0 + row) * NH + head;                                  \
      lw[jj] = lacc[li] + la1[li];                                            \
    }                                                                         \
  }

#define WO_WRITEBUF(boff)                                                     \
  {                                                                           \
    _Pragma("unroll") for (int jj = 0; jj < 2; ++jj) {                        \
      const int j = wave * 2 + jj;                                            \
      const float inv = 1.0f / lw[jj];                                        \
      const float4 a0 = Aa[jj][0], a1 = Aa[jj][1];                            \
      const float4 b0 = Ab[jj][0], b1 = Ab[jj][1];                            \
      const float4 w0 = Bw[jj][0], w1 = Bw[jj][1];                            \
      ushort8 ah = {f2bf((a0.x + b0.x) * inv), f2bf((a0.y + b0.y) * inv),     \
                    f2bf((a0.z + b0.z) * inv), f2bf((a0.w + b0.w) * inv),     \
                    f2bf((a1.x + b1.x) * inv), f2bf((a1.y + b1.y) * inv),     \
                    f2bf((a1.z + b1.z) * inv), f2bf((a1.w + b1.w) * inv)};    \
      ushort8 bh = {f2bf(w0.x), f2bf(w0.y), f2bf(w0.z), f2bf(w0.w),           \
                    f2bf(w1.x), f2bf(w1.y), f2bf(w1.z), f2bf(w1.w)};          \
      *(ushort8*)&sA[(boff) + j * 512 + lane * 8] = ah;                       \
      *(ushort8*)&sB[(boff) + j * 512 + lane * 8] = bh;                       \
    }                                                                         \
  }

  WO_LOADSTEP(0);
  WO_WRITEBUF(0);
  WO_LOADSTEP(1);
  __syncthreads();

  for (int k = 0; k < nstep; ++k) {
    const int cb = (k & 1) * 4096;
    if (k + 1 < nstep) {
      const int nb = ((k + 1) & 1) * 4096;
      WO_WRITEBUF(nb);
      if (k + 2 < nstep) WO_LOADSTEP(k + 2);
    }

    short8 afh[4];
#pragma unroll
    for (int mt = 0; mt < 4; ++mt) {
      const int row = wm * 64 + mt * 16 + n15;
      afh[mt] = *(const short8*)&sA[cb + row * 32 + ((quad ^ (n15 >> 2)) << 3)];
    }
#pragma unroll
    for (int nt = 0; nt < 4; ++nt) {
      const int row = wn * 64 + nt * 16 + n15;
      const short8 bfh = *(const short8*)&sB[cb + row * 32 + ((quad ^ (n15 >> 2)) << 3)];
#pragma unroll
      for (int mt = 0; mt < 4; ++mt)
        acc[mt][nt] = __builtin_amdgcn_mfma_f32_16x16x32_bf16(afh[mt], bfh, acc[mt][nt], 0, 0, 0);
    }
    __syncthreads();
  }

  float* wslab = woout + (size_t)kz * B1 * DMODEL;
#pragma unroll
  for (int mt = 0; mt < 4; ++mt)
#pragma unroll
    for (int nt = 0; nt < 4; ++nt)
#pragma unroll
      for (int rr = 0; rr < 4; ++rr) {
        const int row = m0 + wm * 64 + mt * 16 + quad * 4 + rr;
        const int col = n0 + wn * 64 + nt * 16 + n15;
        wslab[(size_t)row * DMODEL + col] = acc[mt][nt][rr];
      }
#undef WO_LOADSTEP
#undef WO_WRITEBUF
}

// ---------------------------------------------------------------------------
// Final row l2norm, summing the 3 wo split-K slabs.
// ---------------------------------------------------------------------------
__global__ __launch_bounds__(256) void l2norm_rows768_out(
    const float* __restrict__ x, float* __restrict__ out) {
  const int row = blockIdx.x;
  const float* x0 = &x[(size_t)row * DMODEL];
  const float* x1s = x0 + (size_t)B1 * DMODEL;
  const float* x2s = x0 + 2 * (size_t)B1 * DMODEL;
  float ss = 0.0f;
  float vals[3];
#pragma unroll
  for (int i = 0; i < 3; ++i) {
    const int c = threadIdx.x + i * 256;
    vals[i] = x0[c] + x1s[c] + x2s[c];
    ss += vals[i] * vals[i];
  }
#pragma unroll
  for (int off = 32; off > 0; off >>= 1) ss += __shfl_xor(ss, off, 64);
  __shared__ float ws[4];
  if ((threadIdx.x & 63) == 0) ws[threadIdx.x >> 6] = ss;
  __syncthreads();
  const float tot = ws[0] + ws[1] + ws[2] + ws[3];
  const float sc = 1.0f / fmaxf(sqrtf(tot), 1e-12f);
  float* orow = &out[(size_t)row * DMODEL];
#pragma unroll
  for (int i = 0; i < 3; ++i) orow[threadIdx.x + i * 256] = vals[i] * sc;
}

// ---------------------------------------------------------------------------
extern "C" void kernel_launch(void* const* d_in, const int* in_sizes, int n_in,
                              void* d_out, int out_size, void* d_ws,
                              size_t ws_size, hipStream_t stream) {
  const float* x1 = (const float*)d_in[0];
  const float* x2 = (const float*)d_in[1];
  const float* Wq = (const float*)d_in[2];
  const float* Wk = (const float*)d_in[3];
  const float* Wv = (const float*)d_in[4];
  const float* Wo = (const float*)d_in[5];
  const int* invt = (const int*)d_in[6];
  float* outp = (float*)d_out;

  // workspace (bytes):
  //  aoacc 2 slabs   [0,        12582912)
  //  woout 3 slabs   [12582912, 31457280)  (slab1/2 overlay vt region,
  //                                         which is dead after attn)
  //  vt_bf           [18874368, 31457280)
  //  lacc 2 slabs    [32636928, 32833536)
  //  q_bf            [38535168, 41680896)
  //  k_bf            [41680896, 54263808)
  char* ws = (char*)d_ws;
  float* aoacc = (float*)(ws + 0);
  float* woout = (float*)(ws + 12582912);
  unsigned short* vt_bf = (unsigned short*)(ws + 18874368);
  float* lacc = (float*)(ws + 32636928);
  unsigned short* q_bf = (unsigned short*)(ws + 38535168);
  unsigned short* k_bf = (unsigned short*)(ws + 41680896);

  // 1) q+k+v projections, segment-local XCD swizzle, dbuf staging
  qkv_proj<<<864, 256, 0, stream>>>(x1, Wq, x2, Wk, Wv, q_bf, k_bf, vt_bf);
  // 2) attention (R8-verified pipeline, unchanged)
  attn_mfma<<<768, 256, 0, stream>>>(q_bf, k_bf, vt_bf, aoacc, lacc, invt);
  // 3) Wo projection, split-K x3, per-kz-segment swizzle, dbuf staging
  wo_proj<<<288, 256, 0, stream>>>(aoacc, lacc, Wo, woout);
  // 4) final row l2norm over 3 slabs
  l2norm_rows768_out<<<B1, 256, 0, stream>>>(woout, outp);
}

// Round 15
// 270.288 us; speedup vs baseline: 1.1193x; 1.0037x over previous
//
#include <hip/hip_runtime.h>
#include <hip/hip_bf16.h>
#include <math.h>

#define B1 2048
#define B2 8192
#define NH 12
#define DH 64
#define DMODEL 768

typedef __attribute__((ext_vector_type(8))) short short8;
typedef __attribute__((ext_vector_type(4))) float floatx4;
typedef __attribute__((ext_vector_type(8))) unsigned short ushort8;
typedef __attribute__((ext_vector_type(4))) unsigned short ushort4v;

static __device__ __forceinline__ unsigned short f2bf(float f) {
  __bf16 b = (__bf16)f;
  return __builtin_bit_cast(unsigned short, b);
}

// ---------------------------------------------------------------------------
// f32-source bf16 MFMA GEMM tile: C[M,N] = bf16(A[M,K]) * bf16(B[N,K])^T.
// 128x128 tile, BK=32, 4 waves (2x2), 64x64/wave.
// LDS double-buffered, ONE barrier per k-step (R8/R13-verified invariant).
// Staging: reg-pipelined f32 loads one k-step ahead, cvt at write.
// L2N: per-64-col L2 norm epilogue.
// ---------------------------------------------------------------------------
template <bool L2N, bool F32OUT>
static __device__ __forceinline__ void gemm_tile_f32(
    const float* __restrict__ Ag, const float* __restrict__ Bg,
    void* __restrict__ Cv, int M, int N, int K, int m0, int n0,
    unsigned short* sA, unsigned short* sB) {  // each [2][4096] shorts
  const int tid = threadIdx.x;
  const int wave = tid >> 6;
  const int lane = tid & 63;
  const int wm = wave >> 1;
  const int wn = wave & 1;
  const int n15 = lane & 15;
  const int quad = lane >> 4;
  const int srow = lane >> 2;
  const int cpl = (lane & 3) ^ (srow >> 2);
  const int nstep = K >> 5;

  floatx4 acc[4][4];
#pragma unroll
  for (int i = 0; i < 4; ++i)
#pragma unroll
    for (int j = 0; j < 4; ++j) acc[i][j] = (floatx4){0.f, 0.f, 0.f, 0.f};

  float4 ar[2][2], br[2][2];
  // load k-step 0
#pragma unroll
  for (int jj = 0; jj < 2; ++jj) {
    const int row = (wave * 2 + jj) * 16 + srow;
    const size_t ga = (size_t)(m0 + row) * K + cpl * 8;
    const size_t gb = (size_t)(n0 + row) * K + cpl * 8;
    ar[jj][0] = *(const float4*)&Ag[ga];
    ar[jj][1] = *(const float4*)&Ag[ga + 4];
    br[jj][0] = *(const float4*)&Bg[gb];
    br[jj][1] = *(const float4*)&Bg[gb + 4];
  }
  // write buf0
#pragma unroll
  for (int jj = 0; jj < 2; ++jj) {
    const int j = wave * 2 + jj;
    const float4 a0 = ar[jj][0], a1 = ar[jj][1];
    const float4 b0 = br[jj][0], b1 = br[jj][1];
    ushort8 ah = {f2bf(a0.x), f2bf(a0.y), f2bf(a0.z), f2bf(a0.w),
                  f2bf(a1.x), f2bf(a1.y), f2bf(a1.z), f2bf(a1.w)};
    ushort8 bh = {f2bf(b0.x), f2bf(b0.y), f2bf(b0.z), f2bf(b0.w),
                  f2bf(b1.x), f2bf(b1.y), f2bf(b1.z), f2bf(b1.w)};
    *(ushort8*)&sA[j * 512 + lane * 8] = ah;
    *(ushort8*)&sB[j * 512 + lane * 8] = bh;
  }
  // load k-step 1
  if (nstep > 1) {
#pragma unroll
    for (int jj = 0; jj < 2; ++jj) {
      const int row = (wave * 2 + jj) * 16 + srow;
      const size_t ga = (size_t)(m0 + row) * K + 32 + cpl * 8;
      const size_t gb = (size_t)(n0 + row) * K + 32 + cpl * 8;
      ar[jj][0] = *(const float4*)&Ag[ga];
      ar[jj][1] = *(const float4*)&Ag[ga + 4];
      br[jj][0] = *(const float4*)&Bg[gb];
      br[jj][1] = *(const float4*)&Bg[gb + 4];
    }
  }
  __syncthreads();

  for (int k = 0; k < nstep; ++k) {
    const int cb = (k & 1) * 4096;
    if (k + 1 < nstep) {
      const int nb = ((k + 1) & 1) * 4096;
#pragma unroll
      for (int jj = 0; jj < 2; ++jj) {
        const int j = wave * 2 + jj;
        const float4 a0 = ar[jj][0], a1 = ar[jj][1];
        const float4 b0 = br[jj][0], b1 = br[jj][1];
        ushort8 ah = {f2bf(a0.x), f2bf(a0.y), f2bf(a0.z), f2bf(a0.w),
                      f2bf(a1.x), f2bf(a1.y), f2bf(a1.z), f2bf(a1.w)};
        ushort8 bh = {f2bf(b0.x), f2bf(b0.y), f2bf(b0.z), f2bf(b0.w),
                      f2bf(b1.x), f2bf(b1.y), f2bf(b1.z), f2bf(b1.w)};
        *(ushort8*)&sA[nb + j * 512 + lane * 8] = ah;
        *(ushort8*)&sB[nb + j * 512 + lane * 8] = bh;
      }
      if (k + 2 < nstep) {
#pragma unroll
        for (int jj = 0; jj < 2; ++jj) {
          const int row = (wave * 2 + jj) * 16 + srow;
          const size_t ga = (size_t)(m0 + row) * K + (k + 2) * 32 + cpl * 8;
          const size_t gb = (size_t)(n0 + row) * K + (k + 2) * 32 + cpl * 8;
          ar[jj][0] = *(const float4*)&Ag[ga];
          ar[jj][1] = *(const float4*)&Ag[ga + 4];
          br[jj][0] = *(const float4*)&Bg[gb];
          br[jj][1] = *(const float4*)&Bg[gb + 4];
        }
      }
    }

    short8 afh[4];
#pragma unroll
    for (int mt = 0; mt < 4; ++mt) {
      const int row = wm * 64 + mt * 16 + n15;
      afh[mt] = *(const short8*)&sA[cb + row * 32 + ((quad ^ (n15 >> 2)) << 3)];
    }
#pragma unroll
    for (int nt = 0; nt < 4; ++nt) {
      const int row = wn * 64 + nt * 16 + n15;
      const short8 bfh = *(const short8*)&sB[cb + row * 32 + ((quad ^ (n15 >> 2)) << 3)];
#pragma unroll
      for (int mt = 0; mt < 4; ++mt)
        acc[mt][nt] = __builtin_amdgcn_mfma_f32_16x16x32_bf16(afh[mt], bfh, acc[mt][nt], 0, 0, 0);
    }
    __syncthreads();  // publish next buf; parity readers of cb are done
  }

#pragma unroll
  for (int mt = 0; mt < 4; ++mt) {
    float scalev[4] = {1.f, 1.f, 1.f, 1.f};
    if constexpr (L2N) {
#pragma unroll
      for (int rr = 0; rr < 4; ++rr) {
        float ss = 0.f;
#pragma unroll
        for (int nt = 0; nt < 4; ++nt) ss += acc[mt][nt][rr] * acc[mt][nt][rr];
        ss += __shfl_xor(ss, 1, 64);
        ss += __shfl_xor(ss, 2, 64);
        ss += __shfl_xor(ss, 4, 64);
        ss += __shfl_xor(ss, 8, 64);
        scalev[rr] = 1.0f / fmaxf(sqrtf(ss), 1e-12f);
      }
    }
#pragma unroll
    for (int nt = 0; nt < 4; ++nt) {
#pragma unroll
      for (int rr = 0; rr < 4; ++rr) {
        const int row = m0 + wm * 64 + mt * 16 + quad * 4 + rr;
        const int col = n0 + wn * 64 + nt * 16 + n15;
        const float v = acc[mt][nt][rr] * scalev[rr];
        if constexpr (F32OUT)
          ((float*)Cv)[(size_t)row * N + col] = v;
        else
          ((unsigned short*)Cv)[(size_t)row * N + col] = f2bf(v);
      }
    }
  }
}

// ---------------------------------------------------------------------------
// Fused q+k+v projections, one launch (864 blocks), f32 sources.
// Segment-local XCD swizzle (R14-verified). R15: v-GEMM tile mapping is
// N-MAJOR (m0 = b%6, n0 = b/6) so consecutive logical blocks share the
// x2 B-panel (393 KB) instead of the tiny Wv A-panel (2.4 MB, caches
// machine-wide anyway) -> x2 HBM traffic in v-GEMM ~150 MB -> ~25 MB.
// Bonus: XCD i touches x2 panels 8i..8i+7 in BOTH the k-GEMM (A-side) and
// v-GEMM (B-side) -> cross-GEMM L2 reuse.
// [0,96) q (L2N) | [96,480) k (L2N) | [480,864) v.
// ---------------------------------------------------------------------------
__global__ __launch_bounds__(256) void qkv_proj(
    const float* __restrict__ x1, const float* __restrict__ Wq,
    const float* __restrict__ x2, const float* __restrict__ Wk,
    const float* __restrict__ Wv,
    unsigned short* __restrict__ qbf, unsigned short* __restrict__ kbf,
    unsigned short* __restrict__ vtbf) {
  __shared__ __align__(16) unsigned short sA[8192], sB[8192];  // 2 bufs each
  const int bid = blockIdx.x;
  if (bid < 96) {
    const int b = (bid & 7) * 12 + (bid >> 3);            // 96 = 8*12
    gemm_tile_f32<true, false>(x1, Wq, qbf, B1, DMODEL, DMODEL,
                               (b / 6) * 128, (b % 6) * 128, sA, sB);
  } else if (bid < 480) {
    const int lb = bid - 96;
    const int b = (lb & 7) * 48 + (lb >> 3);              // 384 = 8*48
    gemm_tile_f32<true, false>(x2, Wk, kbf, B2, DMODEL, DMODEL,
                               (b / 6) * 128, (b % 6) * 128, sA, sB);
  } else {
    const int lb = bid - 480;
    const int b = (lb & 7) * 48 + (lb >> 3);              // 384 = 8*48
    gemm_tile_f32<false, false>(Wv, x2, vtbf, DMODEL, B2, DMODEL,
                                (b % 6) * 128, (b / 6) * 128, sA, sB);
  }
}

// ---------------------------------------------------------------------------
// MFMA bf16 attention — R8-verified structure (byte-identical to R14).
// ---------------------------------------------------------------------------
#define KC 128
#define KSPLIT 2
#define NCH (B2 / KSPLIT / KC)  // 32
#define PSTR 68

__global__ __launch_bounds__(256, 3) void attn_mfma(
    const unsigned short* __restrict__ qb, const unsigned short* __restrict__ kb,
    const unsigned short* __restrict__ vt, float* __restrict__ aoacc,
    float* __restrict__ lacc, const int* __restrict__ invt_p) {
  __shared__ __align__(16) unsigned short smem[25088];  // 50176 B
  unsigned short* Psl = smem + 16384;   // 4 waves x 32 x PSTR

  const int bid = blockIdx.x;                     // 0..767
  const int swz = (bid & 7) * 96 + (bid >> 3);    // bijective (768 % 8 == 0)
  const int zz = swz / 384;
  const int rem = swz - zz * 384;
  const int h = rem >> 5;
  const int q0 = (rem & 31) * 64;

  const float c2 = (float)invt_p[0] * 1.4426950408889634f;
  const int tid = threadIdx.x;
  const int wave = tid >> 6;
  const int lane = tid & 63;
  const int qsub = wave >> 1;
  const int ksub = wave & 1;
  const int n15 = lane & 15;
  const int quad = lane >> 4;
  const int kz0 = zz * (B2 / KSPLIT);

  unsigned short* Ps = &Psl[wave * 32 * PSTR];

  short8 qf[2][2];
#pragma unroll
  for (int qt = 0; qt < 2; ++qt)
#pragma unroll
    for (int ks = 0; ks < 2; ++ks) {
      const int qrow = q0 + qsub * 32 + qt * 16 + n15;
      qf[qt][ks] = *(const short8*)&qb[(size_t)qrow * DMODEL + h * DH + ks * 32 + quad * 8];
    }

  floatx4 oacc[2][4];
#pragma unroll
  for (int qt = 0; qt < 2; ++qt)
#pragma unroll
    for (int nt = 0; nt < 4; ++nt) oacc[qt][nt] = (floatx4){0.f, 0.f, 0.f, 0.f};
  float lsum[2] = {0.f, 0.f};

  const unsigned short* kbp = kb + (size_t)kz0 * DMODEL + h * DH;
  const unsigned short* vbp = vt + (size_t)(h * DH) * B2 + kz0;

  // prologue: load K chunk0 -> stage buf0 -> load K chunk1 -> barrier
  ushort8 kr[4];
#pragma unroll
  for (int i = 0; i < 4; ++i) {
    const int s = i * 256 + tid;
    const int key = s >> 3, cpk = s & 7, chk = cpk ^ (key & 7);
    kr[i] = *(const ushort8*)&kbp[(size_t)key * DMODEL + chk * 8];
  }
#pragma unroll
  for (int i = 0; i < 4; ++i) {
    const int s = i * 256 + tid;
    const int key = s >> 3, cpk = s & 7;
    *(ushort8*)&smem[key * 64 + cpk * 8] = kr[i];
  }
#pragma unroll
  for (int i = 0; i < 4; ++i) {
    const int s = i * 256 + tid;
    const int key = s >> 3, cpk = s & 7, chk = cpk ^ (key & 7);
    kr[i] = *(const ushort8*)&kbp[(size_t)(KC + key) * DMODEL + chk * 8];
  }
  __syncthreads();

  for (int c = 0; c < NCH; ++c) {
    unsigned short* Kb = &smem[(c & 1) * 8192];
    unsigned short* Kn = &smem[((c + 1) & 1) * 8192];
    const unsigned short* vc_ = vbp + c * KC;

    // early V issue for THIS chunk (consumed in PV below)
    ushort8 vr[8];
#pragma unroll
    for (int ks = 0; ks < 2; ++ks)
#pragma unroll
      for (int nt = 0; nt < 4; ++nt)
        vr[ks * 4 + nt] = *(const ushort8*)&vc_[
            (size_t)(nt * 16 + n15) * B2 + (ksub * 8 + ks * 4 + quad) * 8];

    // stage chunk c+1 into the other buffer; load chunk c+2
    if (c + 1 < NCH) {
#pragma unroll
      for (int i = 0; i < 4; ++i) {
        const int s = i * 256 + tid;
        const int key = s >> 3, cpk = s & 7;
        *(ushort8*)&Kn[key * 64 + cpk * 8] = kr[i];
      }
      if (c + 2 < NCH) {
        const unsigned short* k2 = kbp + (size_t)(c + 2) * KC * DMODEL;
#pragma unroll
        for (int i = 0; i < 4; ++i) {
          const int s = i * 256 + tid;
          const int key = s >> 3, cpk = s & 7, chk = cpk ^ (key & 7);
          kr[i] = *(const ushort8*)&k2[(size_t)key * DMODEL + chk * 8];
        }
      }
    }

    // ---- QK^T from Kb ----
#pragma unroll
    for (int kt = 0; kt < 4; ++kt) {
      floatx4 s0 = {0.f, 0.f, 0.f, 0.f}, s1 = {0.f, 0.f, 0.f, 0.f};
#pragma unroll
      for (int ks = 0; ks < 2; ++ks) {
        const int key = ksub * 64 + kt * 16 + n15;
        const int cp = (ks * 4 + quad) ^ (n15 & 7);
        const short8 kf = *(const short8*)&Kb[key * 64 + cp * 8];
        s0 = __builtin_amdgcn_mfma_f32_16x16x32_bf16(kf, qf[0][ks], s0, 0, 0, 0);
        s1 = __builtin_amdgcn_mfma_f32_16x16x32_bf16(kf, qf[1][ks], s1, 0, 0, 0);
      }
      ushort4v p0, p1;
#pragma unroll
      for (int r = 0; r < 4; ++r) {
        const float e0 = exp2f(fmaf(s0[r], c2, -c2));
        const float e1 = exp2f(fmaf(s1[r], c2, -c2));
        lsum[0] += e0;
        lsum[1] += e1;
        p0[r] = f2bf(e0);
        p1[r] = f2bf(e1);
      }
      *(ushort4v*)&Ps[(0 * 16 + n15) * PSTR + kt * 16 + quad * 4] = p0;
      *(ushort4v*)&Ps[(1 * 16 + n15) * PSTR + kt * 16 + quad * 4] = p1;
    }

    // ---- PV using prefetched vr ----
#pragma unroll
    for (int ks = 0; ks < 2; ++ks) {
      short8 pa[2];
#pragma unroll
      for (int qt = 0; qt < 2; ++qt)
        pa[qt] = *(const short8*)&Ps[(qt * 16 + n15) * PSTR + ks * 32 + quad * 8];
#pragma unroll
      for (int nt = 0; nt < 4; ++nt) {
        const short8 vf = __builtin_bit_cast(short8, vr[ks * 4 + nt]);
        oacc[0][nt] = __builtin_amdgcn_mfma_f32_16x16x32_bf16(pa[0], vf, oacc[0][nt], 0, 0, 0);
        oacc[1][nt] = __builtin_amdgcn_mfma_f32_16x16x32_bf16(pa[1], vf, oacc[1][nt], 0, 0, 0);
      }
    }

    __syncthreads();  // publish Kn; prior Kb readers done before next overwrite
  }

#pragma unroll
  for (int qt = 0; qt < 2; ++qt) {
    float v = lsum[qt];
    v += __shfl_xor(v, 16, 64);
    v += __shfl_xor(v, 32, 64);
    lsum[qt] = v;
  }

  float* aoz = aoacc + (size_t)zz * B1 * DMODEL;
  float* lz = lacc + (size_t)zz * B1 * NH;

  __syncthreads();
  float* Osc = (float*)smem;        // [64 q][64 d] f32 = 16384 B
  float* lsc = Osc + 4096;          // [64 q] f32 (total 16640 <= 50176)
  if (ksub == 1) {
#pragma unroll
    for (int qt = 0; qt < 2; ++qt)
#pragma unroll
      for (int nt = 0; nt < 4; ++nt)
#pragma unroll
        for (int r = 0; r < 4; ++r) {
          const int row = qsub * 32 + qt * 16 + quad * 4 + r;
          Osc[row * 64 + nt * 16 + n15] = oacc[qt][nt][r];
        }
    if (quad == 0) {
      lsc[qsub * 32 + n15] = lsum[0];
      lsc[qsub * 32 + 16 + n15] = lsum[1];
    }
  }
  __syncthreads();
  if (ksub == 0) {
#pragma unroll
    for (int qt = 0; qt < 2; ++qt)
#pragma unroll
      for (int nt = 0; nt < 4; ++nt)
#pragma unroll
        for (int r = 0; r < 4; ++r) {
          const int row = qsub * 32 + qt * 16 + quad * 4 + r;
          const float v = oacc[qt][nt][r] + Osc[row * 64 + nt * 16 + n15];
          aoz[(size_t)(q0 + row) * DMODEL + h * DH + nt * 16 + n15] = v;
        }
    if (quad == 0) {
      lz[(size_t)(q0 + qsub * 32 + n15) * NH + h] = lsum[0] + lsc[qsub * 32 + n15];
      lz[(size_t)(q0 + qsub * 32 + 16 + n15) * NH + h] =
          lsum[1] + lsc[qsub * 32 + 16 + n15];
    }
  }
}

// ---------------------------------------------------------------------------
// Wo projection, SPLIT-K x3 (grid 288 = 3 kz slabs x 96 tiles) with
// single-barrier double-buffered staging and per-kz-segment XCD swizzle
// (96 = 8*12, segment bases 0/96/192 all ≡ 0 mod 8).
// A = (ao0+ao1)/lsum cvt bf16, B = bf16(Wo). Output slab kz, summed in l2norm.
// ---------------------------------------------------------------------------
__global__ __launch_bounds__(256) void wo_proj(
    const float* __restrict__ aoacc, const float* __restrict__ lacc,
    const float* __restrict__ Wo, float* __restrict__ woout) {
  __shared__ __align__(16) unsigned short sA[8192], sB[8192];
  const int bid = blockIdx.x;
  const int kz = bid / 96;
  const int lb = bid % 96;
  const int t = (lb & 7) * 12 + (lb >> 3);   // segment-local XCD swizzle
  const int m0 = (t / 6) * 128;
  const int n0 = (t % 6) * 128;
  const int kbase = kz * 256;
  const int nstep = 8;  // 256 / 32
  const int tid = threadIdx.x;
  const int wave = tid >> 6;
  const int lane = tid & 63;
  const int wm = wave >> 1;
  const int wn = wave & 1;
  const int n15 = lane & 15;
  const int quad = lane >> 4;
  const int srow = lane >> 2;
  const int cpl = (lane & 3) ^ (srow >> 2);

  const float* ao1 = aoacc + (size_t)B1 * DMODEL;
  const float* la1 = lacc + (size_t)B1 * NH;

  floatx4 acc[4][4];
#pragma unroll
  for (int i = 0; i < 4; ++i)
#pragma unroll
    for (int j = 0; j < 4; ++j) acc[i][j] = (floatx4){0.f, 0.f, 0.f, 0.f};

  float4 Aa[2][2], Ab[2][2], Bw[2][2];
  float lw[2];

#define WO_LOADSTEP(s)                                                        \
  {                                                                           \
    const int kk = kbase + (s) * 32;                                          \
    _Pragma("unroll") for (int jj = 0; jj < 2; ++jj) {                        \
      const int row = (wave * 2 + jj) * 16 + srow;                            \
      const size_t ga = (size_t)(m0 + row) * DMODEL + kk + cpl * 8;           \
      const size_t gb = (size_t)(n0 + row) * DMODEL + kk + cpl * 8;           \
      Aa[jj][0] = *(const float4*)&aoacc[ga];                                 \
      Aa[jj][1] = *(const float4*)&aoacc[ga + 4];                             \
      Ab[jj][0] = *(const float4*)&ao1[ga];                                   \
      Ab[jj][1] = *(const float4*)&ao1[ga + 4];                               \
      Bw[jj][0] = *(const float4*)&Wo[gb];                                    \
      Bw[jj][1] = *(const float4*)&Wo[gb + 4];                                \
      const int head = (kk + cpl * 8) >> 6;                                   \
      const int li = (m0 + row) * NH + head;                                  \
      lw[jj] = lacc[li] + la1[li];                                            \
    }                                                                         \
  }

#define WO_WRITEBUF(boff)                                                     \
  {                                                                           \
    _Pragma("unroll") for (int jj = 0; jj < 2; ++jj) {                        \
      const int j = wave * 2 + jj;                                            \
      const float inv = 1.0f / lw[jj];                                        \
      const float4 a0 = Aa[jj][0], a1 = Aa[jj][1];                            \
      const float4 b0 = Ab[jj][0], b1 = Ab[jj][1];                            \
      const float4 w0 = Bw[jj][0], w1 = Bw[jj][1];                            \
      ushort8 ah = {f2bf((a0.x + b0.x) * inv), f2bf((a0.y + b0.y) * inv),     \
                    f2bf((a0.z + b0.z) * inv), f2bf((a0.w + b0.w) * inv),     \
                    f2bf((a1.x + b1.x) * inv), f2bf((a1.y + b1.y) * inv),     \
                    f2bf((a1.z + b1.z) * inv), f2bf((a1.w + b1.w) * inv)};    \
      ushort8 bh = {f2bf(w0.x), f2bf(w0.y), f2bf(w0.z), f2bf(w0.w),           \
                    f2bf(w1.x), f2bf(w1.y), f2bf(w1.z), f2bf(w1.w)};          \
      *(ushort8*)&sA[(boff) + j * 512 + lane * 8] = ah;                       \
      *(ushort8*)&sB[(boff) + j * 512 + lane * 8] = bh;                       \
    }                                                                         \
  }

  WO_LOADSTEP(0);
  WO_WRITEBUF(0);
  WO_LOADSTEP(1);
  __syncthreads();

  for (int k = 0; k < nstep; ++k) {
    const int cb = (k & 1) * 4096;
    if (k + 1 < nstep) {
      const int nb = ((k + 1) & 1) * 4096;
      WO_WRITEBUF(nb);
      if (k + 2 < nstep) WO_LOADSTEP(k + 2);
    }

    short8 afh[4];
#pragma unroll
    for (int mt = 0; mt < 4; ++mt) {
      const int row = wm * 64 + mt * 16 + n15;
      afh[mt] = *(const short8*)&sA[cb + row * 32 + ((quad ^ (n15 >> 2)) << 3)];
    }
#pragma unroll
    for (int nt = 0; nt < 4; ++nt) {
      const int row = wn * 64 + nt * 16 + n15;
      const short8 bfh = *(const short8*)&sB[cb + row * 32 + ((quad ^ (n15 >> 2)) << 3)];
#pragma unroll
      for (int mt = 0; mt < 4; ++mt)
        acc[mt][nt] = __builtin_amdgcn_mfma_f32_16x16x32_bf16(afh[mt], bfh, acc[mt][nt], 0, 0, 0);
    }
    __syncthreads();
  }

  float* wslab = woout + (size_t)kz * B1 * DMODEL;
#pragma unroll
  for (int mt = 0; mt < 4; ++mt)
#pragma unroll
    for (int nt = 0; nt < 4; ++nt)
#pragma unroll
      for (int rr = 0; rr < 4; ++rr) {
        const int row = m0 + wm * 64 + mt * 16 + quad * 4 + rr;
        const int col = n0 + wn * 64 + nt * 16 + n15;
        wslab[(size_t)row * DMODEL + col] = acc[mt][nt][rr];
      }
#undef WO_LOADSTEP
#undef WO_WRITEBUF
}

// ---------------------------------------------------------------------------
// Final row l2norm, summing the 3 wo split-K slabs.
// ---------------------------------------------------------------------------
__global__ __launch_bounds__(256) void l2norm_rows768_out(
    const float* __restrict__ x, float* __restrict__ out) {
  const int row = blockIdx.x;
  const float* x0 = &x[(size_t)row * DMODEL];
  const float* x1s = x0 + (size_t)B1 * DMODEL;
  const float* x2s = x0 + 2 * (size_t)B1 * DMODEL;
  float ss = 0.0f;
  float vals[3];
#pragma unroll
  for (int i = 0; i < 3; ++i) {
    const int c = threadIdx.x + i * 256;
    vals[i] = x0[c] + x1s[c] + x2s[c];
    ss += vals[i] * vals[i];
  }
#pragma unroll
  for (int off = 32; off > 0; off >>= 1) ss += __shfl_xor(ss, off, 64);
  __shared__ float ws[4];
  if ((threadIdx.x & 63) == 0) ws[threadIdx.x >> 6] = ss;
  __syncthreads();
  const float tot = ws[0] + ws[1] + ws[2] + ws[3];
  const float sc = 1.0f / fmaxf(sqrtf(tot), 1e-12f);
  float* orow = &out[(size_t)row * DMODEL];
#pragma unroll
  for (int i = 0; i < 3; ++i) orow[threadIdx.x + i * 256] = vals[i] * sc;
}

// ---------------------------------------------------------------------------
extern "C" void kernel_launch(void* const* d_in, const int* in_sizes, int n_in,
                              void* d_out, int out_size, void* d_ws,
                              size_t ws_size, hipStream_t stream) {
  const float* x1 = (const float*)d_in[0];
  const float* x2 = (const float*)d_in[1];
  const float* Wq = (const float*)d_in[2];
  const float* Wk = (const float*)d_in[3];
  const float* Wv = (const float*)d_in[4];
  const float* Wo = (const float*)d_in[5];
  const int* invt = (const int*)d_in[6];
  float* outp = (float*)d_out;

  // workspace (bytes):
  //  aoacc 2 slabs   [0,        12582912)
  //  woout 3 slabs   [12582912, 31457280)  (slab1/2 overlay vt region,
  //                                         which is dead after attn)
  //  vt_bf           [18874368, 31457280)
  //  lacc 2 slabs    [32636928, 32833536)
  //  q_bf            [38535168, 41680896)
  //  k_bf            [41680896, 54263808)
  char* ws = (char*)d_ws;
  float* aoacc = (float*)(ws + 0);
  float* woout = (float*)(ws + 12582912);
  unsigned short* vt_bf = (unsigned short*)(ws + 18874368);
  float* lacc = (float*)(ws + 32636928);
  unsigned short* q_bf = (unsigned short*)(ws + 38535168);
  unsigned short* k_bf = (unsigned short*)(ws + 41680896);

  // 1) q+k+v projections, segment-local swizzle, v-GEMM n-major mapping
  qkv_proj<<<864, 256, 0, stream>>>(x1, Wq, x2, Wk, Wv, q_bf, k_bf, vt_bf);
  // 2) attention (R8-verified pipeline, unchanged)
  attn_mfma<<<768, 256, 0, stream>>>(q_bf, k_bf, vt_bf, aoacc, lacc, invt);
  // 3) Wo projection, split-K x3, per-kz-segment swizzle, dbuf staging
  wo_proj<<<288, 256, 0, stream>>>(aoacc, lacc, Wo, woout);
  // 4) final row l2norm over 3 slabs
  l2norm_rows768_out<<<B1, 256, 0, stream>>>(woout, outp);
}